// Round 14
// baseline (309.816 us; speedup 1.0000x reference)
//
#include <hip/hip_runtime.h>

#define BB 4
#define CCH 256
#define NPIX 4096
#define EPS 1e-6f

typedef __attribute__((ext_vector_type(8))) short bf16x8;
typedef __attribute__((ext_vector_type(4))) float f32x4;
typedef __attribute__((ext_vector_type(16))) float f32x16;

__device__ __forceinline__ unsigned short f2bf(float f) {
    return (unsigned short)((__float_as_uint(f) + 0x8000u) >> 16);
}
__device__ __forceinline__ float bf2f(unsigned short h) {
    return __uint_as_float((unsigned)h << 16);
}
__device__ __forceinline__ void gl2lds16(const void* g, void* l) {
    __builtin_amdgcn_global_load_lds(
        (const __attribute__((address_space(1))) unsigned int*)g,
        (__attribute__((address_space(3))) unsigned int*)l, 16, 0, 0);
}
// combine two bf16x2 words: (a+b)*f per lane, repack to bf16x2
__device__ __forceinline__ unsigned int comb2(unsigned int u0, unsigned int u1,
                                              float f) {
    float lo = (bf2f((unsigned short)u0) + bf2f((unsigned short)u1)) * f;
    float hi = (bf2f((unsigned short)(u0 >> 16)) +
                bf2f((unsigned short)(u1 >> 16))) * f;
    return (unsigned int)f2bf(lo) | ((unsigned int)f2bf(hi) << 16);
}

// ------- Kernel 1: fused GroupNorm (stats + apply) + weight cvt -------
// Blocks 0..127: one block per (b,g). Stats pass reads the group's 128 KB
// slice (L2-resident), wave-shfl + 8-slot LDS reduce, then the apply pass
// re-reads from L2 and writes sb[n][c] bf16 (transposed). Blocks 128..159:
// weights fp32 -> bf16 (order p,q,k,v), 512 threads each.
__global__ __launch_bounds__(512) void gn_fused(
    const float* __restrict__ x, const float* __restrict__ gamma,
    const float* __restrict__ beta,
    const float* __restrict__ wq, const float* __restrict__ wk,
    const float* __restrict__ wv, const float* __restrict__ wp,
    unsigned short* __restrict__ sb, unsigned short* __restrict__ wb) {
    int bid = blockIdx.x;
    int t = threadIdx.x;
    if (bid >= 128) {                     // folded weight conversion
        int e = (bid - 128) * 512 + t;    // float4 index, 0..16383
        const float* srcs[4] = {wp, wq, wk, wv};
#pragma unroll
        for (int m = 0; m < 4; ++m) {
            float4 v = ((const float4*)srcs[m])[e];
            ushort4 hh;
            hh.x = f2bf(v.x); hh.y = f2bf(v.y);
            hh.z = f2bf(v.z); hh.w = f2bf(v.w);
            *(ushort4*)(wb + (size_t)m * 65536 + (size_t)e * 4) = hh;
        }
        return;
    }
    int b = bid >> 5, g = bid & 31;
    const float4* x4 = (const float4*)(x + (size_t)(b * CCH + g * 8) * NPIX);
    float s = 0.f, ss = 0.f;
    for (int e = t; e < 8192; e += 512) {
        float4 v = x4[e];
        s += v.x + v.y + v.z + v.w;
        ss += v.x * v.x + v.y * v.y + v.z * v.z + v.w * v.w;
    }
#pragma unroll
    for (int off = 1; off < 64; off <<= 1) {
        s += __shfl_xor(s, off);
        ss += __shfl_xor(ss, off);
    }
    __shared__ float ws[8], wss[8];
    int w = t >> 6, lane = t & 63;
    if (lane == 0) { ws[w] = s; wss[w] = ss; }
    __syncthreads();
    float S = 0.f, SS = 0.f;
#pragma unroll
    for (int i = 0; i < 8; ++i) { S += ws[i]; SS += wss[i]; }
    const float inv = 1.0f / (float)(8 * NPIX);
    float m = S * inv;
    float var = SS * inv - m * m;
    float rstd = rsqrtf(var + EPS);
    float scale[8], shift[8];
#pragma unroll
    for (int ci = 0; ci < 8; ++ci) {
        float ga = gamma[g * 8 + ci], be = beta[g * 8 + ci];
        scale[ci] = rstd * ga;
        shift[ci] = be - m * scale[ci];
    }
#pragma unroll 1
    for (int r = 0; r < 2; ++r) {
        int pq = r * 512 + t;                    // pixel-quad 0..1023
        __align__(16) unsigned short hh[4][8];
#pragma unroll
        for (int ci = 0; ci < 8; ++ci) {
            float4 v = x4[ci * 1024 + pq];       // L2-hit re-read
            hh[0][ci] = f2bf(v.x * scale[ci] + shift[ci]);
            hh[1][ci] = f2bf(v.y * scale[ci] + shift[ci]);
            hh[2][ci] = f2bf(v.z * scale[ci] + shift[ci]);
            hh[3][ci] = f2bf(v.w * scale[ci] + shift[ci]);
        }
        size_t base = ((size_t)(b * NPIX + pq * 4) << 8) + g * 8;
#pragma unroll
        for (int p = 0; p < 4; ++p)
            *(uint4*)(sb + base + (size_t)p * 256) = *(const uint4*)hh[p];
    }
}

// ------- Kernel 3: QKV MFMA GEMM (R11-verified, unchanged) -------
// C[n][co] = sum_c sb[n][c] * w[co][c]; block tile 128n x 128co, BK=64.
// z: 0=q (scaled, ->qT[n][c]), 1=k (->kT[n][c]), 2=v (->vB[c][n]).
__global__ __launch_bounds__(256) void qkv_mfma(
    const unsigned short* __restrict__ sb, const unsigned short* __restrict__ wb,
    const float* __restrict__ bq, const float* __restrict__ bk,
    const float* __restrict__ bv,
    unsigned short* __restrict__ qT, unsigned short* __restrict__ kT,
    unsigned short* __restrict__ vB) {
    __shared__ __align__(16) char lds[34816];
    const int tid = threadIdx.x, lane = tid & 63, w = tid >> 6;
    const int ln15 = lane & 15, q = lane >> 4;
    const int n0 = blockIdx.x * 128;
    const int co0 = blockIdx.y * 128;
    const int z = blockIdx.z;
    const unsigned short* wm = wb + (size_t)(z + 1) * 65536;
    const float* bias = (z == 0) ? bq : (z == 1) ? bk : bv;

    f32x4 acc[2][8];
#pragma unroll
    for (int i2 = 0; i2 < 2; ++i2)
#pragma unroll
        for (int nf = 0; nf < 8; ++nf) {
            acc[i2][nf][0] = 0.f; acc[i2][nf][1] = 0.f;
            acc[i2][nf][2] = 0.f; acc[i2][nf][3] = 0.f;
        }

#pragma unroll 1
    for (int kt = 0; kt < 4; ++kt) {
#pragma unroll
        for (int r = 0; r < 4; ++r) {
            int gch = r * 256 + tid;
            int row = gch >> 3, sidx = gch & 7;
            int cc = sidx ^ (row & 7);
            gl2lds16(sb + ((size_t)(n0 + row) << 8) + kt * 64 + cc * 8,
                     &lds[r * 4096 + w * 1024]);
            gl2lds16(wm + ((size_t)(co0 + row) << 8) + kt * 64 + cc * 8,
                     &lds[16384 + r * 4096 + w * 1024]);
        }
        __syncthreads();
#pragma unroll
        for (int kk = 0; kk < 2; ++kk) {
            int kc = kk * 4 + q;
            bf16x8 af[2], bf[8];
#pragma unroll
            for (int i2 = 0; i2 < 2; ++i2) {
                int row = w * 32 + i2 * 16 + ln15;
                af[i2] = *(const bf16x8*)&lds[row * 128 + ((kc ^ (row & 7)) << 4)];
            }
#pragma unroll
            for (int nf = 0; nf < 8; ++nf) {
                int row = nf * 16 + ln15;
                bf[nf] = *(const bf16x8*)&lds[16384 + row * 128 + ((kc ^ (row & 7)) << 4)];
            }
#pragma unroll
            for (int i2 = 0; i2 < 2; ++i2)
#pragma unroll
                for (int nf = 0; nf < 8; ++nf)
                    acc[i2][nf] = __builtin_amdgcn_mfma_f32_16x16x32_bf16(
                        af[i2], bf[nf], acc[i2][nf], 0, 0, 0);
        }
        __syncthreads();
    }

    // epilogue: bias (+scale for q), bounce through LDS tile for coalescing
    float bias_l[8];
#pragma unroll
    for (int nf = 0; nf < 8; ++nf) bias_l[nf] = bias[co0 + nf * 16 + ln15];
    const float scl = (z == 0) ? 0.0625f : 1.0f;
    unsigned short* T = (unsigned short*)lds;
    if (z < 2) {
#pragma unroll
        for (int i2 = 0; i2 < 2; ++i2)
#pragma unroll
            for (int nf = 0; nf < 8; ++nf)
#pragma unroll
                for (int r = 0; r < 4; ++r) {
                    int n_l = w * 32 + i2 * 16 + q * 4 + r;
                    int co_l = nf * 16 + ln15;
                    T[n_l * 136 + co_l] = f2bf((acc[i2][nf][r] + bias_l[nf]) * scl);
                }
    } else {
#pragma unroll
        for (int i2 = 0; i2 < 2; ++i2)
#pragma unroll
            for (int nf = 0; nf < 8; ++nf)
#pragma unroll
                for (int r = 0; r < 4; ++r) {
                    int n_l = w * 32 + i2 * 16 + q * 4 + r;
                    int co_l = nf * 16 + ln15;
                    T[co_l * 136 + n_l] = f2bf(acc[i2][nf][r] + bias_l[nf]);
                }
    }
    __syncthreads();
    int row = tid >> 1, half = tid & 1;
    const uint4* src = (const uint4*)&T[row * 136 + half * 64];
    uint4* dst;
    if (z < 2) {
        unsigned short* qk = (z == 0) ? qT : kT;
        dst = (uint4*)(qk + ((size_t)(n0 + row) << 8) + co0 + half * 64);
    } else {
        int b2 = n0 >> 12, pix0 = n0 & 4095;
        dst = (uint4*)(vB + ((size_t)(b2 * CCH + co0 + row) << 12) + pix0 + half * 64);
    }
#pragma unroll
    for (int u = 0; u < 8; ++u) dst[u] = src[u];
}

// ------- Kernel 4: flash attention, 32x32x16 MFMA, direct-L2 V -------
// R13 structure, but V is NOT staged through LDS: each block's V slice
// (2 MB, pinned to its XCD's L2 by the bx%8=(b,bjh) decode) is read
// directly into registers as the PV B-fragment — per lane a contiguous
// 16 B of vB[c][j] (no swizzle needed; values identical to the staged
// path since the stage/read swizzles cancelled). This removes ~1/3 of
// the LDS-pipe traffic (the pacing pipe at ~77% busy) and shrinks LDS
// to K dbuf 64K + P 16K = 80 KB.
// Waitcnt discipline: NO manual vmcnt. Per iter (after bar1): issue
// K_{t+1} gl2lds, then the 8 vg global loads, then QK/softmax/bar2/PV.
// PV's register use of vg forces the compiler's vmcnt to retire all
// OLDER VMEM entries — including K_{t+1} — so K_t is always resident and
// published at bar1(t) with no explicit drain (prologue __syncthreads
// fully drains K_0). P-slab reuse is guarded by bar1 (PV_{t-1} pf reads
// lgkm-complete before their MFMAs); K-buffer reuse by bar2(t-1).
// LDS: K0 0 | K1 32K | P 64K..80K.
__global__ __launch_bounds__(512, 1) void attn_mfma(
    const unsigned short* __restrict__ qT, const unsigned short* __restrict__ kT,
    const unsigned short* __restrict__ vB,
    unsigned short* __restrict__ pO, float* __restrict__ pml) {
    __shared__ __align__(16) char lds[81920];
    const int tid = threadIdx.x, lane = tid & 63, w = tid >> 6;   // w 0..7
    const int l31 = lane & 31, lh = lane >> 5;
    const int bx = blockIdx.x;
    const int xk = bx & 7;                // XCD key = (b, bjh)
    const int b = xk >> 1, bjh = xk & 1;
    const int itile = bx >> 3;
    const int i0 = itile * 128;
    const int jbase = bjh * 2048;
    const size_t nb = (size_t)b * NPIX;
    const int iqb = (w >> 1) * 32;        // QK i-group base
    const int jh = w & 1, jwb = jh * 32;  // QK j-subhalf base
    const int ipb = (w & 1) * 64;         // PV i-half base
    const int cqb = (w >> 1) * 64;        // PV c-quarter base
    // V row base pointers for this wave's two c-rows (per-lane)
    const unsigned short* vrow0 = vB + ((size_t)(b * CCH + cqb + l31) << 12);
    const unsigned short* vrow1 = vrow0 + ((size_t)32 << 12);

    // ---- stage Q [128 i][256 c] (64 KB) into K0+K1 region ----
#pragma unroll
    for (int t = 0; t < 8; ++t) {
        int gch = (w * 8 + t) * 64 + lane;
        int row = gch >> 5, sc = gch & 31;
        int cc = sc ^ (row & 7);
        gl2lds16(qT + ((nb + i0 + row) << 8) + cc * 8, &lds[(w * 8 + t) * 1024]);
    }
    __syncthreads();
    bf16x8 qf[16];
    {
        int row = iqb + l31;              // A-frag: row = l&31, k = lh*8+e
#pragma unroll
        for (int kc = 0; kc < 16; ++kc) {
            int sc = kc * 2 + lh;
            qf[kc] = *(const bf16x8*)&lds[row * 512 + ((sc ^ (row & 7)) << 4)];
        }
    }
    __syncthreads();

    f32x16 O[2][2];
#pragma unroll
    for (int ig = 0; ig < 2; ++ig)
#pragma unroll
        for (int cg = 0; cg < 2; ++cg)
#pragma unroll
            for (int r = 0; r < 16; ++r) O[ig][cg][r] = 0.f;
    float l_acc[16];
#pragma unroll
    for (int r = 0; r < 16; ++r) l_acc[r] = 0.f;

    // ---- prologue: K_0 -> K0; full drain + publish ----
    {
        const int j0 = jbase;
#pragma unroll
        for (int t = 0; t < 4; ++t) {
            int gch = (w * 4 + t) * 64 + lane;
            int row = gch >> 5, sc = gch & 31;
            int cc = sc ^ (row & 7);
            gl2lds16(kT + ((nb + j0 + row) << 8) + cc * 8, &lds[(w * 4 + t) * 1024]);
        }
    }
    __syncthreads();                      // K_0 staged & visible

#pragma unroll 1
    for (int jt = 0; jt < 32; ++jt) {
        const int kb_ = (jt & 1) * 32768;          // K buffer base
        const int kbn = ((jt + 1) & 1) * 32768;
        const int j0 = jbase + jt * 64;

        // (1) K_t staged (jt=0: prologue sync; jt>0: prior iter's vg
        // consumption drained everything older, incl. K_t) + P slab free.
        if (jt) __builtin_amdgcn_s_barrier();

        // ---- prefetch K_{t+1} (MUST precede vg: older in VMEM FIFO) ----
        if (jt < 31) {
            const int j0n = j0 + 64;
#pragma unroll
            for (int t = 0; t < 4; ++t) {
                int gch = (w * 4 + t) * 64 + lane;
                int row = gch >> 5, sc = gch & 31;
                int cc = sc ^ (row & 7);
                gl2lds16(kT + ((nb + j0n + row) << 8) + cc * 8,
                         &lds[kbn + (w * 4 + t) * 1024]);
            }
        }

        // ---- V_t direct from L2 -> regs (B-frags, no swizzle) ----
        bf16x8 vg[4][2];
#pragma unroll
        for (int kc = 0; kc < 4; ++kc) {
            int joff = j0 + kc * 16 + lh * 8;
            vg[kc][0] = *(const bf16x8*)(vrow0 + joff);
            vg[kc][1] = *(const bf16x8*)(vrow1 + joff);
        }

        // ---- QK: S[32 i][32 j], two independent chains over K=256 ----
        f32x16 S0, S1;
#pragma unroll
        for (int r = 0; r < 16; ++r) { S0[r] = 0.f; S1[r] = 0.f; }
        __builtin_amdgcn_s_setprio(1);
        {
            int krow = jwb + l31;                // B-frag: col = l&31 (j)
            int ksw = kb_ + krow * 512;
#pragma unroll
            for (int kc = 0; kc < 8; ++kc) {
                int sc0 = (2 * kc) * 2 + lh;
                int sc1 = (2 * kc + 1) * 2 + lh;
                bf16x8 k0 = *(const bf16x8*)&lds[ksw + ((sc0 ^ (krow & 7)) << 4)];
                bf16x8 k1 = *(const bf16x8*)&lds[ksw + ((sc1 ^ (krow & 7)) << 4)];
                S0 = __builtin_amdgcn_mfma_f32_32x32x16_bf16(qf[2 * kc], k0, S0, 0, 0, 0);
                S1 = __builtin_amdgcn_mfma_f32_32x32x16_bf16(qf[2 * kc + 1], k1, S1, 0, 0, 0);
            }
        }
        __builtin_amdgcn_s_setprio(0);

        // ---- fixed-max softmax: p = exp(s); P -> slab; l per-lane ----
        {
            int col = jwb + l31;
            int chs = (col >> 3) << 4;
            int cof = (col & 7) << 1;
#pragma unroll
            for (int r = 0; r < 16; ++r) {
                float p = __expf(S0[r] + S1[r]);
                l_acc[r] += p;
                int row = iqb + (r & 3) + 8 * (r >> 2) + 4 * lh;
                *(unsigned short*)&lds[65536 + row * 128 +
                    (chs ^ ((row & 7) << 4)) + cof] = f2bf(p);
            }
        }
        asm volatile("s_waitcnt lgkmcnt(0)" ::: "memory");  // own P writes landed
        __builtin_amdgcn_sched_barrier(0);
        __builtin_amdgcn_s_barrier();            // (2) P visible + QK_t done

        // ---- PV: O[64 i][64 c] += P[64 i][64 j] V[64 j][64 c] ----
        __builtin_amdgcn_s_setprio(1);
        {
            int pr0 = ipb + l31, pr1 = ipb + 32 + l31;   // P A-frag rows
#pragma unroll
            for (int kc = 0; kc < 4; ++kc) {
                int pc = kc * 2 + lh;                     // j-chunk index
                bf16x8 pf0 = *(const bf16x8*)&lds[65536 + pr0 * 128 + ((pc ^ (pr0 & 7)) << 4)];
                bf16x8 pf1 = *(const bf16x8*)&lds[65536 + pr1 * 128 + ((pc ^ (pr1 & 7)) << 4)];
                O[0][0] = __builtin_amdgcn_mfma_f32_32x32x16_bf16(pf0, vg[kc][0], O[0][0], 0, 0, 0);
                O[0][1] = __builtin_amdgcn_mfma_f32_32x32x16_bf16(pf0, vg[kc][1], O[0][1], 0, 0, 0);
                O[1][0] = __builtin_amdgcn_mfma_f32_32x32x16_bf16(pf1, vg[kc][0], O[1][0], 0, 0, 0);
                O[1][1] = __builtin_amdgcn_mfma_f32_32x32x16_bf16(pf1, vg[kc][1], O[1][1], 0, 0, 0);
            }
        }
        __builtin_amdgcn_s_setprio(0);
    }

    // ---- epilogue: unnormalized partial O (bf16) + deferred l reduce ----
    size_t pbase = (size_t)bx * (128 * 256);
#pragma unroll
    for (int ig = 0; ig < 2; ++ig)
#pragma unroll
        for (int cg = 0; cg < 2; ++cg)
#pragma unroll
            for (int r = 0; r < 16; ++r) {
                int i = ipb + ig * 32 + (r & 3) + 8 * (r >> 2) + 4 * lh;
                int c = cqb + cg * 32 + l31;
                pO[pbase + i * 256 + c] = f2bf(O[ig][cg][r]);
            }
#pragma unroll
    for (int r = 0; r < 16; ++r) {
        float l = l_acc[r];
        l += __shfl_xor(l, 1);
        l += __shfl_xor(l, 2);
        l += __shfl_xor(l, 4);
        l += __shfl_xor(l, 8);
        l += __shfl_xor(l, 16);
        if (l31 == 0) {                          // lanes 0 and 32 (rows +4 apart)
            int row = iqb + (r & 3) + 8 * (r >> 2) + 4 * lh;
            pml[bx * 256 + jh * 128 + row] = l;  // j-subhalf partial row sum
        }
    }
}

// ------- Kernel 6: proj MFMA GEMM with fused j-partial merge -------
// A-operand is reg-staged from the 2 pO partials, combined as
// (o0+o1)*fs[row] (fs from pml, precomputed in LDS), and written to the
// EXACT LDS image gl2lds produced (addr = r*4096 + w*1024 + lane*16).
// B (weights) stays gl2lds. Epilogue: bias + residual -> out fp32.
__global__ __launch_bounds__(256) void proj_mfma(
    const unsigned short* __restrict__ pO, const float* __restrict__ pml,
    const unsigned short* __restrict__ wb, const float* __restrict__ bp,
    const float* __restrict__ x, float* __restrict__ out) {
    __shared__ __align__(16) char lds[35328];    // 34816 + 512 for fs
    float* fs = (float*)&lds[34816];
    const int tid = threadIdx.x, lane = tid & 63, w = tid >> 6;
    const int ln15 = lane & 15, q = lane >> 4;
    const int n0 = blockIdx.x * 128;
    const int co0 = blockIdx.y * 128;

    if (tid < 128) {                      // 1/l for the block's 128 rows
        int n = n0 + tid;
        int bb = n >> 12, pix = n & 4095, it = pix >> 7, ii = pix & 127;
        int base = (it * 8 + bb * 2) * 256 + ii;
        float l = pml[base] + pml[base + 128] + pml[base + 256] + pml[base + 384];
        fs[tid] = 1.0f / l;
    }
    __syncthreads();

    f32x4 acc[2][8];
#pragma unroll
    for (int i2 = 0; i2 < 2; ++i2)
#pragma unroll
        for (int nf = 0; nf < 8; ++nf) {
            acc[i2][nf][0] = 0.f; acc[i2][nf][1] = 0.f;
            acc[i2][nf][2] = 0.f; acc[i2][nf][3] = 0.f;
        }

#pragma unroll 1
    for (int kt = 0; kt < 4; ++kt) {
#pragma unroll
        for (int r = 0; r < 4; ++r) {     // B staging (gl2lds, unchanged)
            int gch = r * 256 + tid;
            int row = gch >> 3, sidx = gch & 7;
            int cc = sidx ^ (row & 7);
            gl2lds16(wb + ((size_t)(co0 + row) << 8) + kt * 64 + cc * 8,
                     &lds[16384 + r * 4096 + w * 1024]);
        }
#pragma unroll
        for (int r = 0; r < 4; ++r) {     // A staging: merge-on-load from pO
            int gch = r * 256 + tid;
            int row = gch >> 3, sidx = gch & 7;
            int cc = sidx ^ (row & 7);
            int c = kt * 64 + cc * 8;
            int n = n0 + row;
            int bb = n >> 12, pix = n & 4095, it = pix >> 7, ii = pix & 127;
            size_t pb = (size_t)(it * 8 + bb * 2) * 32768 + (size_t)ii * 256 + c;
            uint4 a0 = *(const uint4*)&pO[pb];
            uint4 a1 = *(const uint4*)&pO[pb + 32768];
            float f = fs[row];
            uint4 o;
            o.x = comb2(a0.x, a1.x, f);
            o.y = comb2(a0.y, a1.y, f);
            o.z = comb2(a0.z, a1.z, f);
            o.w = comb2(a0.w, a1.w, f);
            *(uint4*)&lds[r * 4096 + w * 1024 + lane * 16] = o;
        }
        __syncthreads();
#pragma unroll
        for (int kk = 0; kk < 2; ++kk) {
            int kc = kk * 4 + q;
            bf16x8 af[2], bf[8];
#pragma unroll
            for (int i2 = 0; i2 < 2; ++i2) {
                int row = w * 32 + i2 * 16 + ln15;
                af[i2] = *(const bf16x8*)&lds[row * 128 + ((kc ^ (row & 7)) << 4)];
            }
#pragma unroll
            for (int nf = 0; nf < 8; ++nf) {
                int row = nf * 16 + ln15;
                bf[nf] = *(const bf16x8*)&lds[16384 + row * 128 + ((kc ^ (row & 7)) << 4)];
            }
#pragma unroll
            for (int i2 = 0; i2 < 2; ++i2)
#pragma unroll
                for (int nf = 0; nf < 8; ++nf)
                    acc[i2][nf] = __builtin_amdgcn_mfma_f32_16x16x32_bf16(
                        af[i2], bf[nf], acc[i2][nf], 0, 0, 0);
        }
        __syncthreads();
    }

    unsigned short* T = (unsigned short*)lds;
#pragma unroll
    for (int i2 = 0; i2 < 2; ++i2)
#pragma unroll
        for (int nf = 0; nf < 8; ++nf)
#pragma unroll
            for (int r = 0; r < 4; ++r) {
                int n_l = w * 32 + i2 * 16 + q * 4 + r;
                int co_l = nf * 16 + ln15;
                T[co_l * 136 + n_l] = f2bf(acc[i2][nf][r]);
            }
    __syncthreads();
    int row = tid >> 1, half = tid & 1;       // row = co_local
    int b2 = n0 >> 12, pix0 = n0 & 4095;
    float br = bp[co0 + row];
    size_t gidx = (((size_t)(b2 * CCH + co0 + row)) << 12) + pix0 + half * 64;
    const unsigned short* trow = &T[row * 136 + half * 64];
#pragma unroll
    for (int u = 0; u < 16; ++u) {
        float4 xv = *(const float4*)&x[gidx + u * 4];
        ushort4 tv = *(const ushort4*)&trow[u * 4];
        float4 o;
        o.x = xv.x + br + bf2f(tv.x);
        o.y = xv.y + br + bf2f(tv.y);
        o.z = xv.z + br + bf2f(tv.z);
        o.w = xv.w + br + bf2f(tv.w);
        *(float4*)&out[gidx + u * 4] = o;
    }
}

extern "C" void kernel_launch(void* const* d_in, const int* in_sizes, int n_in,
                              void* d_out, int out_size, void* d_ws, size_t ws_size,
                              hipStream_t stream) {
    const float* x     = (const float*)d_in[0];
    const float* gamma = (const float*)d_in[1];
    const float* beta  = (const float*)d_in[2];
    const float* wq    = (const float*)d_in[3];
    const float* bq    = (const float*)d_in[4];
    const float* wk    = (const float*)d_in[5];
    const float* bk    = (const float*)d_in[6];
    const float* wv    = (const float*)d_in[7];
    const float* bv    = (const float*)d_in[8];
    const float* wp    = (const float*)d_in[9];
    const float* bp    = (const float*)d_in[10];
    float* out = (float*)d_out;

    char* p = (char*)d_ws;
    unsigned short* sb  = (unsigned short*)p; p += 8388608;        // 8 MB
    unsigned short* wb  = (unsigned short*)p; p += 524288;         // 512 KB
    unsigned short* pO  = (unsigned short*)p; p += 16777216;       // 16 MB
    float*          pml = (float*)p;          p += 262144;         // 256 KB
    unsigned short* qT  = (unsigned short*)p; p += 8388608;        // 8 MB
    unsigned short* kT  = (unsigned short*)p; p += 8388608;        // 8 MB
    unsigned short* vB  = (unsigned short*)p;                      // 8 MB

    gn_fused<<<160, 512, 0, stream>>>(x, gamma, beta, wq, wk, wv, wp, sb, wb);
    qkv_mfma<<<dim3(128, 2, 3), 256, 0, stream>>>(sb, wb, bq, bk, bv, qT, kT, vB);
    attn_mfma<<<256, 512, 0, stream>>>(qT, kT, vB, pO, pml);
    proj_mfma<<<dim3(128, 2), 256, 0, stream>>>(pO, pml, wb, bp, x, out);
}

// Round 15
// 210.118 us; speedup vs baseline: 1.4745x; 1.4745x over previous
//
#include <hip/hip_runtime.h>

#define BB 4
#define CCH 256
#define NPIX 4096
#define EPS 1e-6f

typedef __attribute__((ext_vector_type(8))) short bf16x8;
typedef __attribute__((ext_vector_type(4))) float f32x4;
typedef __attribute__((ext_vector_type(16))) float f32x16;

__device__ __forceinline__ unsigned short f2bf(float f) {
    return (unsigned short)((__float_as_uint(f) + 0x8000u) >> 16);
}
__device__ __forceinline__ float bf2f(unsigned short h) {
    return __uint_as_float((unsigned)h << 16);
}
__device__ __forceinline__ void gl2lds16(const void* g, void* l) {
    __builtin_amdgcn_global_load_lds(
        (const __attribute__((address_space(1))) unsigned int*)g,
        (__attribute__((address_space(3))) unsigned int*)l, 16, 0, 0);
}
// combine two bf16x2 words: (a+b)*f per lane, repack to bf16x2
__device__ __forceinline__ unsigned int comb2(unsigned int u0, unsigned int u1,
                                              float f) {
    float lo = (bf2f((unsigned short)u0) + bf2f((unsigned short)u1)) * f;
    float hi = (bf2f((unsigned short)(u0 >> 16)) +
                bf2f((unsigned short)(u1 >> 16))) * f;
    return (unsigned int)f2bf(lo) | ((unsigned int)f2bf(hi) << 16);
}

// ------- Kernel 1: fused GroupNorm (stats + apply) + weight cvt -------
// Blocks 0..127: one block per (b,g). Stats pass reads the group's 128 KB
// slice (L2-resident), wave-shfl + 8-slot LDS reduce, then the apply pass
// re-reads from L2 and writes sb[n][c] bf16 (transposed). Blocks 128..159:
// weights fp32 -> bf16 (order p,q,k,v), 512 threads each.
__global__ __launch_bounds__(512) void gn_fused(
    const float* __restrict__ x, const float* __restrict__ gamma,
    const float* __restrict__ beta,
    const float* __restrict__ wq, const float* __restrict__ wk,
    const float* __restrict__ wv, const float* __restrict__ wp,
    unsigned short* __restrict__ sb, unsigned short* __restrict__ wb) {
    int bid = blockIdx.x;
    int t = threadIdx.x;
    if (bid >= 128) {                     // folded weight conversion
        int e = (bid - 128) * 512 + t;    // float4 index, 0..16383
        const float* srcs[4] = {wp, wq, wk, wv};
#pragma unroll
        for (int m = 0; m < 4; ++m) {
            float4 v = ((const float4*)srcs[m])[e];
            ushort4 hh;
            hh.x = f2bf(v.x); hh.y = f2bf(v.y);
            hh.z = f2bf(v.z); hh.w = f2bf(v.w);
            *(ushort4*)(wb + (size_t)m * 65536 + (size_t)e * 4) = hh;
        }
        return;
    }
    int b = bid >> 5, g = bid & 31;
    const float4* x4 = (const float4*)(x + (size_t)(b * CCH + g * 8) * NPIX);
    float s = 0.f, ss = 0.f;
    for (int e = t; e < 8192; e += 512) {
        float4 v = x4[e];
        s += v.x + v.y + v.z + v.w;
        ss += v.x * v.x + v.y * v.y + v.z * v.z + v.w * v.w;
    }
#pragma unroll
    for (int off = 1; off < 64; off <<= 1) {
        s += __shfl_xor(s, off);
        ss += __shfl_xor(ss, off);
    }
    __shared__ float ws[8], wss[8];
    int w = t >> 6, lane = t & 63;
    if (lane == 0) { ws[w] = s; wss[w] = ss; }
    __syncthreads();
    float S = 0.f, SS = 0.f;
#pragma unroll
    for (int i = 0; i < 8; ++i) { S += ws[i]; SS += wss[i]; }
    const float inv = 1.0f / (float)(8 * NPIX);
    float m = S * inv;
    float var = SS * inv - m * m;
    float rstd = rsqrtf(var + EPS);
    float scale[8], shift[8];
#pragma unroll
    for (int ci = 0; ci < 8; ++ci) {
        float ga = gamma[g * 8 + ci], be = beta[g * 8 + ci];
        scale[ci] = rstd * ga;
        shift[ci] = be - m * scale[ci];
    }
#pragma unroll 1
    for (int r = 0; r < 2; ++r) {
        int pq = r * 512 + t;                    // pixel-quad 0..1023
        __align__(16) unsigned short hh[4][8];
#pragma unroll
        for (int ci = 0; ci < 8; ++ci) {
            float4 v = x4[ci * 1024 + pq];       // L2-hit re-read
            hh[0][ci] = f2bf(v.x * scale[ci] + shift[ci]);
            hh[1][ci] = f2bf(v.y * scale[ci] + shift[ci]);
            hh[2][ci] = f2bf(v.z * scale[ci] + shift[ci]);
            hh[3][ci] = f2bf(v.w * scale[ci] + shift[ci]);
        }
        size_t base = ((size_t)(b * NPIX + pq * 4) << 8) + g * 8;
#pragma unroll
        for (int p = 0; p < 4; ++p)
            *(uint4*)(sb + base + (size_t)p * 256) = *(const uint4*)hh[p];
    }
}

// ------- Kernel 3: QKV MFMA GEMM (R11-verified, unchanged) -------
// C[n][co] = sum_c sb[n][c] * w[co][c]; block tile 128n x 128co, BK=64.
// z: 0=q (scaled, ->qT[n][c]), 1=k (->kT[n][c]), 2=v (->vB[c][n]).
__global__ __launch_bounds__(256) void qkv_mfma(
    const unsigned short* __restrict__ sb, const unsigned short* __restrict__ wb,
    const float* __restrict__ bq, const float* __restrict__ bk,
    const float* __restrict__ bv,
    unsigned short* __restrict__ qT, unsigned short* __restrict__ kT,
    unsigned short* __restrict__ vB) {
    __shared__ __align__(16) char lds[34816];
    const int tid = threadIdx.x, lane = tid & 63, w = tid >> 6;
    const int ln15 = lane & 15, q = lane >> 4;
    const int n0 = blockIdx.x * 128;
    const int co0 = blockIdx.y * 128;
    const int z = blockIdx.z;
    const unsigned short* wm = wb + (size_t)(z + 1) * 65536;
    const float* bias = (z == 0) ? bq : (z == 1) ? bk : bv;

    f32x4 acc[2][8];
#pragma unroll
    for (int i2 = 0; i2 < 2; ++i2)
#pragma unroll
        for (int nf = 0; nf < 8; ++nf) {
            acc[i2][nf][0] = 0.f; acc[i2][nf][1] = 0.f;
            acc[i2][nf][2] = 0.f; acc[i2][nf][3] = 0.f;
        }

#pragma unroll 1
    for (int kt = 0; kt < 4; ++kt) {
#pragma unroll
        for (int r = 0; r < 4; ++r) {
            int gch = r * 256 + tid;
            int row = gch >> 3, sidx = gch & 7;
            int cc = sidx ^ (row & 7);
            gl2lds16(sb + ((size_t)(n0 + row) << 8) + kt * 64 + cc * 8,
                     &lds[r * 4096 + w * 1024]);
            gl2lds16(wm + ((size_t)(co0 + row) << 8) + kt * 64 + cc * 8,
                     &lds[16384 + r * 4096 + w * 1024]);
        }
        __syncthreads();
#pragma unroll
        for (int kk = 0; kk < 2; ++kk) {
            int kc = kk * 4 + q;
            bf16x8 af[2], bf[8];
#pragma unroll
            for (int i2 = 0; i2 < 2; ++i2) {
                int row = w * 32 + i2 * 16 + ln15;
                af[i2] = *(const bf16x8*)&lds[row * 128 + ((kc ^ (row & 7)) << 4)];
            }
#pragma unroll
            for (int nf = 0; nf < 8; ++nf) {
                int row = nf * 16 + ln15;
                bf[nf] = *(const bf16x8*)&lds[16384 + row * 128 + ((kc ^ (row & 7)) << 4)];
            }
#pragma unroll
            for (int i2 = 0; i2 < 2; ++i2)
#pragma unroll
                for (int nf = 0; nf < 8; ++nf)
                    acc[i2][nf] = __builtin_amdgcn_mfma_f32_16x16x32_bf16(
                        af[i2], bf[nf], acc[i2][nf], 0, 0, 0);
        }
        __syncthreads();
    }

    // epilogue: bias (+scale for q), bounce through LDS tile for coalescing
    float bias_l[8];
#pragma unroll
    for (int nf = 0; nf < 8; ++nf) bias_l[nf] = bias[co0 + nf * 16 + ln15];
    const float scl = (z == 0) ? 0.0625f : 1.0f;
    unsigned short* T = (unsigned short*)lds;
    if (z < 2) {
#pragma unroll
        for (int i2 = 0; i2 < 2; ++i2)
#pragma unroll
            for (int nf = 0; nf < 8; ++nf)
#pragma unroll
                for (int r = 0; r < 4; ++r) {
                    int n_l = w * 32 + i2 * 16 + q * 4 + r;
                    int co_l = nf * 16 + ln15;
                    T[n_l * 136 + co_l] = f2bf((acc[i2][nf][r] + bias_l[nf]) * scl);
                }
    } else {
#pragma unroll
        for (int i2 = 0; i2 < 2; ++i2)
#pragma unroll
            for (int nf = 0; nf < 8; ++nf)
#pragma unroll
                for (int r = 0; r < 4; ++r) {
                    int n_l = w * 32 + i2 * 16 + q * 4 + r;
                    int co_l = nf * 16 + ln15;
                    T[co_l * 136 + n_l] = f2bf(acc[i2][nf][r] + bias_l[nf]);
                }
    }
    __syncthreads();
    int row = tid >> 1, half = tid & 1;
    const uint4* src = (const uint4*)&T[row * 136 + half * 64];
    uint4* dst;
    if (z < 2) {
        unsigned short* qk = (z == 0) ? qT : kT;
        dst = (uint4*)(qk + ((size_t)(n0 + row) << 8) + co0 + half * 64);
    } else {
        int b2 = n0 >> 12, pix0 = n0 & 4095;
        dst = (uint4*)(vB + ((size_t)(b2 * CCH + co0 + row) << 12) + pix0 + half * 64);
    }
#pragma unroll
    for (int u = 0; u < 8; ++u) dst[u] = src[u];
}

// ------- Kernel 4: flash attention, 32x32x16 MFMA, dbuf K/V, 2 barriers ----
// 256 blocks (b, jh half of j, itile of 128 i): bx = itile*8 + b*2 + jh;
// bx%8 = (b,jh) pins each XCD to a fixed 2 MB K/V slice (R2-verified).
// 8 waves / 512 threads, 32 j-tiles of 64. Double-buffered K and V, 1-ahead
// prefetch: barrier1 = {K_t ready (vmcnt 4), P slab free}; barrier2 =
// {P visible (lgkmcnt 0), V_t ready (vmcnt 0), all QK_t done}. K_{t+1} is
// issued after barrier2; V_{t+1} after PV_t. Fixed-max softmax
// (R2-verified): p = exp(s) exactly, l per-lane, reduced in epilogue as
// j-subhalf partials. launch_bounds(512,1): LDS (144K) caps occupancy at
// 1 block/CU anyway, so no VGPR cap -> no spill.
// LDS: K0 0|K1 32K|V0 64K|V1 96K|P 128K..144K.
__global__ __launch_bounds__(512, 1) void attn_mfma(
    const unsigned short* __restrict__ qT, const unsigned short* __restrict__ kT,
    const unsigned short* __restrict__ vB,
    unsigned short* __restrict__ pO, float* __restrict__ pml) {
    __shared__ __align__(16) char lds[147456];
    const int tid = threadIdx.x, lane = tid & 63, w = tid >> 6;   // w 0..7
    const int l31 = lane & 31, lh = lane >> 5;
    const int bx = blockIdx.x;
    const int xk = bx & 7;                // XCD key = (b, bjh)
    const int b = xk >> 1, bjh = xk & 1;
    const int itile = bx >> 3;
    const int i0 = itile * 128;
    const int jbase = bjh * 2048;
    const size_t nb = (size_t)b * NPIX;
    const int iqb = (w >> 1) * 32;        // QK i-group base
    const int jh = w & 1, jwb = jh * 32;  // QK j-subhalf base
    const int ipb = (w & 1) * 64;         // PV i-half base
    const int cqb = (w >> 1) * 64;        // PV c-quarter base

    // ---- stage Q [128 i][256 c] (64 KB) into K0+K1 region ----
#pragma unroll
    for (int t = 0; t < 8; ++t) {
        int gch = (w * 8 + t) * 64 + lane;
        int row = gch >> 5, sc = gch & 31;
        int cc = sc ^ (row & 7);
        gl2lds16(qT + ((nb + i0 + row) << 8) + cc * 8, &lds[(w * 8 + t) * 1024]);
    }
    __syncthreads();
    bf16x8 qf[16];
    {
        int row = iqb + l31;              // A-frag: row = l&31, k = lh*8+e
#pragma unroll
        for (int kc = 0; kc < 16; ++kc) {
            int sc = kc * 2 + lh;
            qf[kc] = *(const bf16x8*)&lds[row * 512 + ((sc ^ (row & 7)) << 4)];
        }
    }
    __syncthreads();

    f32x16 O[2][2];
#pragma unroll
    for (int ig = 0; ig < 2; ++ig)
#pragma unroll
        for (int cg = 0; cg < 2; ++cg)
#pragma unroll
            for (int r = 0; r < 16; ++r) O[ig][cg][r] = 0.f;
    float l_acc[16];
#pragma unroll
    for (int r = 0; r < 16; ++r) l_acc[r] = 0.f;

    // ---- prologue prefetch: K_0 -> K0 then V_0 -> V0 ----
    {
        const int j0 = jbase;
#pragma unroll
        for (int t = 0; t < 4; ++t) {
            int gch = (w * 4 + t) * 64 + lane;
            int row = gch >> 5, sc = gch & 31;
            int cc = sc ^ (row & 7);
            gl2lds16(kT + ((nb + j0 + row) << 8) + cc * 8, &lds[(w * 4 + t) * 1024]);
        }
#pragma unroll
        for (int t = 0; t < 4; ++t) {
            int gch = (w * 4 + t) * 64 + lane;
            int c = gch >> 3, sv = gch & 7;
            int jc = sv ^ (c & 7);
            gl2lds16(vB + ((size_t)(b * CCH + c) << 12) + j0 + jc * 8,
                     &lds[65536 + (w * 4 + t) * 1024]);
        }
    }

#pragma unroll 1
    for (int jt = 0; jt < 32; ++jt) {
        const int kb_ = (jt & 1) * 32768;          // K buffer base
        const int vb_ = 65536 + (jt & 1) * 32768;  // V buffer base
        const int kbn = ((jt + 1) & 1) * 32768;
        const int vbn = 65536 + ((jt + 1) & 1) * 32768;

        // ---- K_t ready (oldest 4 loads = K_t; V_t may be in flight) ----
        asm volatile("s_waitcnt vmcnt(4)" ::: "memory");
        __builtin_amdgcn_s_barrier();            // (1) K_t staged, P slab free

        // ---- QK: S[32 i][32 j], two independent chains over K=256 ----
        f32x16 S0, S1;
#pragma unroll
        for (int r = 0; r < 16; ++r) { S0[r] = 0.f; S1[r] = 0.f; }
        __builtin_amdgcn_s_setprio(1);
        {
            int krow = jwb + l31;                // B-frag: col = l&31 (j)
            int ksw = kb_ + krow * 512;
#pragma unroll
            for (int kc = 0; kc < 8; ++kc) {
                int sc0 = (2 * kc) * 2 + lh;
                int sc1 = (2 * kc + 1) * 2 + lh;
                bf16x8 k0 = *(const bf16x8*)&lds[ksw + ((sc0 ^ (krow & 7)) << 4)];
                bf16x8 k1 = *(const bf16x8*)&lds[ksw + ((sc1 ^ (krow & 7)) << 4)];
                S0 = __builtin_amdgcn_mfma_f32_32x32x16_bf16(qf[2 * kc], k0, S0, 0, 0, 0);
                S1 = __builtin_amdgcn_mfma_f32_32x32x16_bf16(qf[2 * kc + 1], k1, S1, 0, 0, 0);
            }
        }
        __builtin_amdgcn_s_setprio(0);

        // ---- fixed-max softmax: p = exp(s); P -> slab; l per-lane ----
        {
            int col = jwb + l31;
            int chs = (col >> 3) << 4;
            int cof = (col & 7) << 1;
#pragma unroll
            for (int r = 0; r < 16; ++r) {
                float p = __expf(S0[r] + S1[r]);
                l_acc[r] += p;
                int row = iqb + (r & 3) + 8 * (r >> 2) + 4 * lh;
                *(unsigned short*)&lds[131072 + row * 128 +
                    (chs ^ ((row & 7) << 4)) + cof] = f2bf(p);
            }
        }
        asm volatile("s_waitcnt lgkmcnt(0)" ::: "memory");  // own P writes landed
        __builtin_amdgcn_sched_barrier(0);
        asm volatile("s_waitcnt vmcnt(0)" ::: "memory");    // V_t staged
        __builtin_amdgcn_s_barrier();            // (2) P visible + V_t + QK_t done

        if (jt < 31) {                           // prefetch K_{t+1} -> other K buf
            const int j0n = jbase + (jt + 1) * 64;
#pragma unroll
            for (int t = 0; t < 4; ++t) {
                int gch = (w * 4 + t) * 64 + lane;
                int row = gch >> 5, sc = gch & 31;
                int cc = sc ^ (row & 7);
                gl2lds16(kT + ((nb + j0n + row) << 8) + cc * 8,
                         &lds[kbn + (w * 4 + t) * 1024]);
            }
        }

        // ---- PV: O[64 i][64 c] += P[64 i][64 j] V[64 j][64 c] ----
        __builtin_amdgcn_s_setprio(1);
        {
            int pr0 = ipb + l31, pr1 = ipb + 32 + l31;   // P A-frag rows
            int vc0 = cqb + l31, vc1 = cqb + 32 + l31;   // V B-frag rows (c)
#pragma unroll
            for (int kc = 0; kc < 4; ++kc) {
                int pc = kc * 2 + lh;                     // j-chunk index
                bf16x8 pf0 = *(const bf16x8*)&lds[131072 + pr0 * 128 + ((pc ^ (pr0 & 7)) << 4)];
                bf16x8 pf1 = *(const bf16x8*)&lds[131072 + pr1 * 128 + ((pc ^ (pr1 & 7)) << 4)];
                bf16x8 vf0 = *(const bf16x8*)&lds[vb_ + vc0 * 128 + ((pc ^ (vc0 & 7)) << 4)];
                bf16x8 vf1 = *(const bf16x8*)&lds[vb_ + vc1 * 128 + ((pc ^ (vc1 & 7)) << 4)];
                O[0][0] = __builtin_amdgcn_mfma_f32_32x32x16_bf16(pf0, vf0, O[0][0], 0, 0, 0);
                O[0][1] = __builtin_amdgcn_mfma_f32_32x32x16_bf16(pf0, vf1, O[0][1], 0, 0, 0);
                O[1][0] = __builtin_amdgcn_mfma_f32_32x32x16_bf16(pf1, vf0, O[1][0], 0, 0, 0);
                O[1][1] = __builtin_amdgcn_mfma_f32_32x32x16_bf16(pf1, vf1, O[1][1], 0, 0, 0);
            }
        }
        __builtin_amdgcn_s_setprio(0);

        if (jt < 31) {                           // prefetch V_{t+1} -> other V buf
            const int j0n = jbase + (jt + 1) * 64;
#pragma unroll
            for (int t = 0; t < 4; ++t) {
                int gch = (w * 4 + t) * 64 + lane;
                int c = gch >> 3, sv = gch & 7;
                int jc = sv ^ (c & 7);
                gl2lds16(vB + ((size_t)(b * CCH + c) << 12) + j0n + jc * 8,
                         &lds[vbn + (w * 4 + t) * 1024]);
            }
        }
    }

    // ---- epilogue: unnormalized partial O (bf16) + deferred l reduce ----
    size_t pbase = (size_t)bx * (128 * 256);
#pragma unroll
    for (int ig = 0; ig < 2; ++ig)
#pragma unroll
        for (int cg = 0; cg < 2; ++cg)
#pragma unroll
            for (int r = 0; r < 16; ++r) {
                int i = ipb + ig * 32 + (r & 3) + 8 * (r >> 2) + 4 * lh;
                int c = cqb + cg * 32 + l31;
                pO[pbase + i * 256 + c] = f2bf(O[ig][cg][r]);
            }
#pragma unroll
    for (int r = 0; r < 16; ++r) {
        float l = l_acc[r];
        l += __shfl_xor(l, 1);
        l += __shfl_xor(l, 2);
        l += __shfl_xor(l, 4);
        l += __shfl_xor(l, 8);
        l += __shfl_xor(l, 16);
        if (l31 == 0) {                          // lanes 0 and 32 (rows +4 apart)
            int row = iqb + (r & 3) + 8 * (r >> 2) + 4 * lh;
            pml[bx * 256 + jh * 128 + row] = l;  // j-subhalf partial row sum
        }
    }
}

// ------- Kernel 6: proj MFMA GEMM with fused j-partial merge -------
// A-operand is reg-staged from the 2 pO partials, combined as
// (o0+o1)*fs[row] (fs from pml, precomputed in LDS), and written to the
// EXACT LDS image gl2lds produced (addr = r*4096 + w*1024 + lane*16).
// B (weights) stays gl2lds. Epilogue: bias + residual -> out fp32.
__global__ __launch_bounds__(256) void proj_mfma(
    const unsigned short* __restrict__ pO, const float* __restrict__ pml,
    const unsigned short* __restrict__ wb, const float* __restrict__ bp,
    const float* __restrict__ x, float* __restrict__ out) {
    __shared__ __align__(16) char lds[35328];    // 34816 + 512 for fs
    float* fs = (float*)&lds[34816];
    const int tid = threadIdx.x, lane = tid & 63, w = tid >> 6;
    const int ln15 = lane & 15, q = lane >> 4;
    const int n0 = blockIdx.x * 128;
    const int co0 = blockIdx.y * 128;

    if (tid < 128) {                      // 1/l for the block's 128 rows
        int n = n0 + tid;
        int bb = n >> 12, pix = n & 4095, it = pix >> 7, ii = pix & 127;
        int base = (it * 8 + bb * 2) * 256 + ii;
        float l = pml[base] + pml[base + 128] + pml[base + 256] + pml[base + 384];
        fs[tid] = 1.0f / l;
    }
    __syncthreads();

    f32x4 acc[2][8];
#pragma unroll
    for (int i2 = 0; i2 < 2; ++i2)
#pragma unroll
        for (int nf = 0; nf < 8; ++nf) {
            acc[i2][nf][0] = 0.f; acc[i2][nf][1] = 0.f;
            acc[i2][nf][2] = 0.f; acc[i2][nf][3] = 0.f;
        }

#pragma unroll 1
    for (int kt = 0; kt < 4; ++kt) {
#pragma unroll
        for (int r = 0; r < 4; ++r) {     // B staging (gl2lds, unchanged)
            int gch = r * 256 + tid;
            int row = gch >> 3, sidx = gch & 7;
            int cc = sidx ^ (row & 7);
            gl2lds16(wb + ((size_t)(co0 + row) << 8) + kt * 64 + cc * 8,
                     &lds[16384 + r * 4096 + w * 1024]);
        }
#pragma unroll
        for (int r = 0; r < 4; ++r) {     // A staging: merge-on-load from pO
            int gch = r * 256 + tid;
            int row = gch >> 3, sidx = gch & 7;
            int cc = sidx ^ (row & 7);
            int c = kt * 64 + cc * 8;
            int n = n0 + row;
            int bb = n >> 12, pix = n & 4095, it = pix >> 7, ii = pix & 127;
            size_t pb = (size_t)(it * 8 + bb * 2) * 32768 + (size_t)ii * 256 + c;
            uint4 a0 = *(const uint4*)&pO[pb];
            uint4 a1 = *(const uint4*)&pO[pb + 32768];
            float f = fs[row];
            uint4 o;
            o.x = comb2(a0.x, a1.x, f);
            o.y = comb2(a0.y, a1.y, f);
            o.z = comb2(a0.z, a1.z, f);
            o.w = comb2(a0.w, a1.w, f);
            *(uint4*)&lds[r * 4096 + w * 1024 + lane * 16] = o;
        }
        __syncthreads();
#pragma unroll
        for (int kk = 0; kk < 2; ++kk) {
            int kc = kk * 4 + q;
            bf16x8 af[2], bf[8];
#pragma unroll
            for (int i2 = 0; i2 < 2; ++i2) {
                int row = w * 32 + i2 * 16 + ln15;
                af[i2] = *(const bf16x8*)&lds[row * 128 + ((kc ^ (row & 7)) << 4)];
            }
#pragma unroll
            for (int nf = 0; nf < 8; ++nf) {
                int row = nf * 16 + ln15;
                bf[nf] = *(const bf16x8*)&lds[16384 + row * 128 + ((kc ^ (row & 7)) << 4)];
            }
#pragma unroll
            for (int i2 = 0; i2 < 2; ++i2)
#pragma unroll
                for (int nf = 0; nf < 8; ++nf)
                    acc[i2][nf] = __builtin_amdgcn_mfma_f32_16x16x32_bf16(
                        af[i2], bf[nf], acc[i2][nf], 0, 0, 0);
        }
        __syncthreads();
    }

    unsigned short* T = (unsigned short*)lds;
#pragma unroll
    for (int i2 = 0; i2 < 2; ++i2)
#pragma unroll
        for (int nf = 0; nf < 8; ++nf)
#pragma unroll
            for (int r = 0; r < 4; ++r) {
                int n_l = w * 32 + i2 * 16 + q * 4 + r;
                int co_l = nf * 16 + ln15;
                T[co_l * 136 + n_l] = f2bf(acc[i2][nf][r]);
            }
    __syncthreads();
    int row = tid >> 1, half = tid & 1;       // row = co_local
    int b2 = n0 >> 12, pix0 = n0 & 4095;
    float br = bp[co0 + row];
    size_t gidx = (((size_t)(b2 * CCH + co0 + row)) << 12) + pix0 + half * 64;
    const unsigned short* trow = &T[row * 136 + half * 64];
#pragma unroll
    for (int u = 0; u < 16; ++u) {
        float4 xv = *(const float4*)&x[gidx + u * 4];
        ushort4 tv = *(const ushort4*)&trow[u * 4];
        float4 o;
        o.x = xv.x + br + bf2f(tv.x);
        o.y = xv.y + br + bf2f(tv.y);
        o.z = xv.z + br + bf2f(tv.z);
        o.w = xv.w + br + bf2f(tv.w);
        *(float4*)&out[gidx + u * 4] = o;
    }
}

extern "C" void kernel_launch(void* const* d_in, const int* in_sizes, int n_in,
                              void* d_out, int out_size, void* d_ws, size_t ws_size,
                              hipStream_t stream) {
    const float* x     = (const float*)d_in[0];
    const float* gamma = (const float*)d_in[1];
    const float* beta  = (const float*)d_in[2];
    const float* wq    = (const float*)d_in[3];
    const float* bq    = (const float*)d_in[4];
    const float* wk    = (const float*)d_in[5];
    const float* bk    = (const float*)d_in[6];
    const float* wv    = (const float*)d_in[7];
    const float* bv    = (const float*)d_in[8];
    const float* wp    = (const float*)d_in[9];
    const float* bp    = (const float*)d_in[10];
    float* out = (float*)d_out;

    char* p = (char*)d_ws;
    unsigned short* sb  = (unsigned short*)p; p += 8388608;        // 8 MB
    unsigned short* wb  = (unsigned short*)p; p += 524288;         // 512 KB
    unsigned short* pO  = (unsigned short*)p; p += 16777216;       // 16 MB
    float*          pml = (float*)p;          p += 262144;         // 256 KB
    unsigned short* qT  = (unsigned short*)p; p += 8388608;        // 8 MB
    unsigned short* kT  = (unsigned short*)p; p += 8388608;        // 8 MB
    unsigned short* vB  = (unsigned short*)p;                      // 8 MB

    gn_fused<<<160, 512, 0, stream>>>(x, gamma, beta, wq, wk, wv, wp, sb, wb);
    qkv_mfma<<<dim3(128, 2, 3), 256, 0, stream>>>(sb, wb, bq, bk, bv, qT, kT, vB);
    attn_mfma<<<256, 512, 0, stream>>>(qT, kT, vB, pO, pml);
    proj_mfma<<<dim3(128, 2), 256, 0, stream>>>(pO, pml, wb, bp, x, out);
}

// Round 16
// 209.915 us; speedup vs baseline: 1.4759x; 1.0010x over previous
//
#include <hip/hip_runtime.h>

#define BB 4
#define CCH 256
#define NPIX 4096
#define EPS 1e-6f

typedef __attribute__((ext_vector_type(8))) short bf16x8;
typedef __attribute__((ext_vector_type(4))) float f32x4;
typedef __attribute__((ext_vector_type(16))) float f32x16;

__device__ __forceinline__ unsigned short f2bf(float f) {
    return (unsigned short)((__float_as_uint(f) + 0x8000u) >> 16);
}
__device__ __forceinline__ float bf2f(unsigned short h) {
    return __uint_as_float((unsigned)h << 16);
}
__device__ __forceinline__ void gl2lds16(const void* g, void* l) {
    __builtin_amdgcn_global_load_lds(
        (const __attribute__((address_space(1))) unsigned int*)g,
        (__attribute__((address_space(3))) unsigned int*)l, 16, 0, 0);
}
// combine two bf16x2 words: (a+b)*f per lane, repack to bf16x2
__device__ __forceinline__ unsigned int comb2(unsigned int u0, unsigned int u1,
                                              float f) {
    float lo = (bf2f((unsigned short)u0) + bf2f((unsigned short)u1)) * f;
    float hi = (bf2f((unsigned short)(u0 >> 16)) +
                bf2f((unsigned short)(u1 >> 16))) * f;
    return (unsigned int)f2bf(lo) | ((unsigned int)f2bf(hi) << 16);
}

// ------- Kernel 1: fused GroupNorm (stats + apply) + weight cvt -------
// Blocks 0..127: one block per (b,g). Stats pass reads the group's 128 KB
// slice (L2-resident), wave-shfl + 8-slot LDS reduce, then the apply pass
// re-reads from L2 and writes sb[n][c] bf16 (transposed). Blocks 128..159:
// weights fp32 -> bf16 (order p,q,k,v), 512 threads each.
__global__ __launch_bounds__(512) void gn_fused(
    const float* __restrict__ x, const float* __restrict__ gamma,
    const float* __restrict__ beta,
    const float* __restrict__ wq, const float* __restrict__ wk,
    const float* __restrict__ wv, const float* __restrict__ wp,
    unsigned short* __restrict__ sb, unsigned short* __restrict__ wb) {
    int bid = blockIdx.x;
    int t = threadIdx.x;
    if (bid >= 128) {                     // folded weight conversion
        int e = (bid - 128) * 512 + t;    // float4 index, 0..16383
        const float* srcs[4] = {wp, wq, wk, wv};
#pragma unroll
        for (int m = 0; m < 4; ++m) {
            float4 v = ((const float4*)srcs[m])[e];
            ushort4 hh;
            hh.x = f2bf(v.x); hh.y = f2bf(v.y);
            hh.z = f2bf(v.z); hh.w = f2bf(v.w);
            *(ushort4*)(wb + (size_t)m * 65536 + (size_t)e * 4) = hh;
        }
        return;
    }
    int b = bid >> 5, g = bid & 31;
    const float4* x4 = (const float4*)(x + (size_t)(b * CCH + g * 8) * NPIX);
    float s = 0.f, ss = 0.f;
    for (int e = t; e < 8192; e += 512) {
        float4 v = x4[e];
        s += v.x + v.y + v.z + v.w;
        ss += v.x * v.x + v.y * v.y + v.z * v.z + v.w * v.w;
    }
#pragma unroll
    for (int off = 1; off < 64; off <<= 1) {
        s += __shfl_xor(s, off);
        ss += __shfl_xor(ss, off);
    }
    __shared__ float ws[8], wss[8];
    int w = t >> 6, lane = t & 63;
    if (lane == 0) { ws[w] = s; wss[w] = ss; }
    __syncthreads();
    float S = 0.f, SS = 0.f;
#pragma unroll
    for (int i = 0; i < 8; ++i) { S += ws[i]; SS += wss[i]; }
    const float inv = 1.0f / (float)(8 * NPIX);
    float m = S * inv;
    float var = SS * inv - m * m;
    float rstd = rsqrtf(var + EPS);
    float scale[8], shift[8];
#pragma unroll
    for (int ci = 0; ci < 8; ++ci) {
        float ga = gamma[g * 8 + ci], be = beta[g * 8 + ci];
        scale[ci] = rstd * ga;
        shift[ci] = be - m * scale[ci];
    }
#pragma unroll 1
    for (int r = 0; r < 2; ++r) {
        int pq = r * 512 + t;                    // pixel-quad 0..1023
        __align__(16) unsigned short hh[4][8];
#pragma unroll
        for (int ci = 0; ci < 8; ++ci) {
            float4 v = x4[ci * 1024 + pq];       // L2-hit re-read
            hh[0][ci] = f2bf(v.x * scale[ci] + shift[ci]);
            hh[1][ci] = f2bf(v.y * scale[ci] + shift[ci]);
            hh[2][ci] = f2bf(v.z * scale[ci] + shift[ci]);
            hh[3][ci] = f2bf(v.w * scale[ci] + shift[ci]);
        }
        size_t base = ((size_t)(b * NPIX + pq * 4) << 8) + g * 8;
#pragma unroll
        for (int p = 0; p < 4; ++p)
            *(uint4*)(sb + base + (size_t)p * 256) = *(const uint4*)hh[p];
    }
}

// ------- Kernel 3: QKV MFMA GEMM (R11-verified, unchanged) -------
// C[n][co] = sum_c sb[n][c] * w[co][c]; block tile 128n x 128co, BK=64.
// z: 0=q (scaled, ->qT[n][c]), 1=k (->kT[n][c]), 2=v (->vB[c][n]).
__global__ __launch_bounds__(256) void qkv_mfma(
    const unsigned short* __restrict__ sb, const unsigned short* __restrict__ wb,
    const float* __restrict__ bq, const float* __restrict__ bk,
    const float* __restrict__ bv,
    unsigned short* __restrict__ qT, unsigned short* __restrict__ kT,
    unsigned short* __restrict__ vB) {
    __shared__ __align__(16) char lds[34816];
    const int tid = threadIdx.x, lane = tid & 63, w = tid >> 6;
    const int ln15 = lane & 15, q = lane >> 4;
    const int n0 = blockIdx.x * 128;
    const int co0 = blockIdx.y * 128;
    const int z = blockIdx.z;
    const unsigned short* wm = wb + (size_t)(z + 1) * 65536;
    const float* bias = (z == 0) ? bq : (z == 1) ? bk : bv;

    f32x4 acc[2][8];
#pragma unroll
    for (int i2 = 0; i2 < 2; ++i2)
#pragma unroll
        for (int nf = 0; nf < 8; ++nf) {
            acc[i2][nf][0] = 0.f; acc[i2][nf][1] = 0.f;
            acc[i2][nf][2] = 0.f; acc[i2][nf][3] = 0.f;
        }

#pragma unroll 1
    for (int kt = 0; kt < 4; ++kt) {
#pragma unroll
        for (int r = 0; r < 4; ++r) {
            int gch = r * 256 + tid;
            int row = gch >> 3, sidx = gch & 7;
            int cc = sidx ^ (row & 7);
            gl2lds16(sb + ((size_t)(n0 + row) << 8) + kt * 64 + cc * 8,
                     &lds[r * 4096 + w * 1024]);
            gl2lds16(wm + ((size_t)(co0 + row) << 8) + kt * 64 + cc * 8,
                     &lds[16384 + r * 4096 + w * 1024]);
        }
        __syncthreads();
#pragma unroll
        for (int kk = 0; kk < 2; ++kk) {
            int kc = kk * 4 + q;
            bf16x8 af[2], bf[8];
#pragma unroll
            for (int i2 = 0; i2 < 2; ++i2) {
                int row = w * 32 + i2 * 16 + ln15;
                af[i2] = *(const bf16x8*)&lds[row * 128 + ((kc ^ (row & 7)) << 4)];
            }
#pragma unroll
            for (int nf = 0; nf < 8; ++nf) {
                int row = nf * 16 + ln15;
                bf[nf] = *(const bf16x8*)&lds[16384 + row * 128 + ((kc ^ (row & 7)) << 4)];
            }
#pragma unroll
            for (int i2 = 0; i2 < 2; ++i2)
#pragma unroll
                for (int nf = 0; nf < 8; ++nf)
                    acc[i2][nf] = __builtin_amdgcn_mfma_f32_16x16x32_bf16(
                        af[i2], bf[nf], acc[i2][nf], 0, 0, 0);
        }
        __syncthreads();
    }

    // epilogue: bias (+scale for q), bounce through LDS tile for coalescing
    float bias_l[8];
#pragma unroll
    for (int nf = 0; nf < 8; ++nf) bias_l[nf] = bias[co0 + nf * 16 + ln15];
    const float scl = (z == 0) ? 0.0625f : 1.0f;
    unsigned short* T = (unsigned short*)lds;
    if (z < 2) {
#pragma unroll
        for (int i2 = 0; i2 < 2; ++i2)
#pragma unroll
            for (int nf = 0; nf < 8; ++nf)
#pragma unroll
                for (int r = 0; r < 4; ++r) {
                    int n_l = w * 32 + i2 * 16 + q * 4 + r;
                    int co_l = nf * 16 + ln15;
                    T[n_l * 136 + co_l] = f2bf((acc[i2][nf][r] + bias_l[nf]) * scl);
                }
    } else {
#pragma unroll
        for (int i2 = 0; i2 < 2; ++i2)
#pragma unroll
            for (int nf = 0; nf < 8; ++nf)
#pragma unroll
                for (int r = 0; r < 4; ++r) {
                    int n_l = w * 32 + i2 * 16 + q * 4 + r;
                    int co_l = nf * 16 + ln15;
                    T[co_l * 136 + n_l] = f2bf(acc[i2][nf][r] + bias_l[nf]);
                }
    }
    __syncthreads();
    int row = tid >> 1, half = tid & 1;
    const uint4* src = (const uint4*)&T[row * 136 + half * 64];
    uint4* dst;
    if (z < 2) {
        unsigned short* qk = (z == 0) ? qT : kT;
        dst = (uint4*)(qk + ((size_t)(n0 + row) << 8) + co0 + half * 64);
    } else {
        int b2 = n0 >> 12, pix0 = n0 & 4095;
        dst = (uint4*)(vB + ((size_t)(b2 * CCH + co0 + row) << 12) + pix0 + half * 64);
    }
#pragma unroll
    for (int u = 0; u < 8; ++u) dst[u] = src[u];
}

// ------- Kernel 4: flash attention, 32x32x16 MFMA, dbuf K/V, 2 barriers ----
// R12 structure; ONLY change: Q/K LDS swizzle widened from 3-bit to 5-bit
// (slot = sc ^ (row & 31), both staging-source and read side). K rows are
// 512 B (bank-phase 0 every row); with the old row&7 swizzle the 32 lanes
// of a QK half-wave (32 distinct rows, same k-chunk) collapsed onto 8
// slots -> 4-way bank conflict on every kf ds_read_b128. With row&31,
// krow&31 = l31 -> 32 distinct slots -> conflict-free. V (8-slot rows,
// gl2lds linear-dest constraint) and P stay as before.
// LDS: K0 0|K1 32K|V0 64K|V1 96K|P 128K..144K.
__global__ __launch_bounds__(512, 1) void attn_mfma(
    const unsigned short* __restrict__ qT, const unsigned short* __restrict__ kT,
    const unsigned short* __restrict__ vB,
    unsigned short* __restrict__ pO, float* __restrict__ pml) {
    __shared__ __align__(16) char lds[147456];
    const int tid = threadIdx.x, lane = tid & 63, w = tid >> 6;   // w 0..7
    const int l31 = lane & 31, lh = lane >> 5;
    const int bx = blockIdx.x;
    const int xk = bx & 7;                // XCD key = (b, bjh)
    const int b = xk >> 1, bjh = xk & 1;
    const int itile = bx >> 3;
    const int i0 = itile * 128;
    const int jbase = bjh * 2048;
    const size_t nb = (size_t)b * NPIX;
    const int iqb = (w >> 1) * 32;        // QK i-group base
    const int jh = w & 1, jwb = jh * 32;  // QK j-subhalf base
    const int ipb = (w & 1) * 64;         // PV i-half base
    const int cqb = (w >> 1) * 64;        // PV c-quarter base

    // ---- stage Q [128 i][256 c] (64 KB) into K0+K1 region (5-bit swz) ----
#pragma unroll
    for (int t = 0; t < 8; ++t) {
        int gch = (w * 8 + t) * 64 + lane;
        int row = gch >> 5, sc = gch & 31;
        int cc = sc ^ (row & 31);
        gl2lds16(qT + ((nb + i0 + row) << 8) + cc * 8, &lds[(w * 8 + t) * 1024]);
    }
    __syncthreads();
    bf16x8 qf[16];
    {
        int row = iqb + l31;              // A-frag: row = l&31, k = lh*8+e
#pragma unroll
        for (int kc = 0; kc < 16; ++kc) {
            int sc = kc * 2 + lh;
            qf[kc] = *(const bf16x8*)&lds[row * 512 + ((sc ^ (row & 31)) << 4)];
        }
    }
    __syncthreads();

    f32x16 O[2][2];
#pragma unroll
    for (int ig = 0; ig < 2; ++ig)
#pragma unroll
        for (int cg = 0; cg < 2; ++cg)
#pragma unroll
            for (int r = 0; r < 16; ++r) O[ig][cg][r] = 0.f;
    float l_acc[16];
#pragma unroll
    for (int r = 0; r < 16; ++r) l_acc[r] = 0.f;

    // ---- prologue prefetch: K_0 -> K0 (5-bit swz) then V_0 -> V0 ----
    {
        const int j0 = jbase;
#pragma unroll
        for (int t = 0; t < 4; ++t) {
            int gch = (w * 4 + t) * 64 + lane;
            int row = gch >> 5, sc = gch & 31;
            int cc = sc ^ (row & 31);
            gl2lds16(kT + ((nb + j0 + row) << 8) + cc * 8, &lds[(w * 4 + t) * 1024]);
        }
#pragma unroll
        for (int t = 0; t < 4; ++t) {
            int gch = (w * 4 + t) * 64 + lane;
            int c = gch >> 3, sv = gch & 7;
            int jc = sv ^ (c & 7);
            gl2lds16(vB + ((size_t)(b * CCH + c) << 12) + j0 + jc * 8,
                     &lds[65536 + (w * 4 + t) * 1024]);
        }
    }

#pragma unroll 1
    for (int jt = 0; jt < 32; ++jt) {
        const int kb_ = (jt & 1) * 32768;          // K buffer base
        const int vb_ = 65536 + (jt & 1) * 32768;  // V buffer base
        const int kbn = ((jt + 1) & 1) * 32768;
        const int vbn = 65536 + ((jt + 1) & 1) * 32768;

        // ---- K_t ready (oldest 4 loads = K_t; V_t may be in flight) ----
        asm volatile("s_waitcnt vmcnt(4)" ::: "memory");
        __builtin_amdgcn_s_barrier();            // (1) K_t staged, P slab free

        // ---- QK: S[32 i][32 j]; kf slots now conflict-free (5-bit swz) ----
        f32x16 S0, S1;
#pragma unroll
        for (int r = 0; r < 16; ++r) { S0[r] = 0.f; S1[r] = 0.f; }
        __builtin_amdgcn_s_setprio(1);
        {
            int krow = jwb + l31;                // B-frag: col = l&31 (j)
            int ksw = kb_ + krow * 512;
            int kx = krow & 31;                  // = l31
#pragma unroll
            for (int kc = 0; kc < 8; ++kc) {
                int sc0 = (2 * kc) * 2 + lh;
                int sc1 = (2 * kc + 1) * 2 + lh;
                bf16x8 k0 = *(const bf16x8*)&lds[ksw + ((sc0 ^ kx) << 4)];
                bf16x8 k1 = *(const bf16x8*)&lds[ksw + ((sc1 ^ kx) << 4)];
                S0 = __builtin_amdgcn_mfma_f32_32x32x16_bf16(qf[2 * kc], k0, S0, 0, 0, 0);
                S1 = __builtin_amdgcn_mfma_f32_32x32x16_bf16(qf[2 * kc + 1], k1, S1, 0, 0, 0);
            }
        }
        __builtin_amdgcn_s_setprio(0);

        // ---- fixed-max softmax: p = exp(s); P -> slab; l per-lane ----
        {
            int col = jwb + l31;
            int chs = (col >> 3) << 4;
            int cof = (col & 7) << 1;
#pragma unroll
            for (int r = 0; r < 16; ++r) {
                float p = __expf(S0[r] + S1[r]);
                l_acc[r] += p;
                int row = iqb + (r & 3) + 8 * (r >> 2) + 4 * lh;
                *(unsigned short*)&lds[131072 + row * 128 +
                    (chs ^ ((row & 7) << 4)) + cof] = f2bf(p);
            }
        }
        asm volatile("s_waitcnt lgkmcnt(0)" ::: "memory");  // own P writes landed
        __builtin_amdgcn_sched_barrier(0);
        asm volatile("s_waitcnt vmcnt(0)" ::: "memory");    // V_t staged
        __builtin_amdgcn_s_barrier();            // (2) P visible + V_t + QK_t done

        if (jt < 31) {                           // prefetch K_{t+1} (5-bit swz)
            const int j0n = jbase + (jt + 1) * 64;
#pragma unroll
            for (int t = 0; t < 4; ++t) {
                int gch = (w * 4 + t) * 64 + lane;
                int row = gch >> 5, sc = gch & 31;
                int cc = sc ^ (row & 31);
                gl2lds16(kT + ((nb + j0n + row) << 8) + cc * 8,
                         &lds[kbn + (w * 4 + t) * 1024]);
            }
        }

        // ---- PV: O[64 i][64 c] += P[64 i][64 j] V[64 j][64 c] ----
        __builtin_amdgcn_s_setprio(1);
        {
            int pr0 = ipb + l31, pr1 = ipb + 32 + l31;   // P A-frag rows
            int vc0 = cqb + l31, vc1 = cqb + 32 + l31;   // V B-frag rows (c)
#pragma unroll
            for (int kc = 0; kc < 4; ++kc) {
                int pc = kc * 2 + lh;                     // j-chunk index
                bf16x8 pf0 = *(const bf16x8*)&lds[131072 + pr0 * 128 + ((pc ^ (pr0 & 7)) << 4)];
                bf16x8 pf1 = *(const bf16x8*)&lds[131072 + pr1 * 128 + ((pc ^ (pr1 & 7)) << 4)];
                bf16x8 vf0 = *(const bf16x8*)&lds[vb_ + vc0 * 128 + ((pc ^ (vc0 & 7)) << 4)];
                bf16x8 vf1 = *(const bf16x8*)&lds[vb_ + vc1 * 128 + ((pc ^ (vc1 & 7)) << 4)];
                O[0][0] = __builtin_amdgcn_mfma_f32_32x32x16_bf16(pf0, vf0, O[0][0], 0, 0, 0);
                O[0][1] = __builtin_amdgcn_mfma_f32_32x32x16_bf16(pf0, vf1, O[0][1], 0, 0, 0);
                O[1][0] = __builtin_amdgcn_mfma_f32_32x32x16_bf16(pf1, vf0, O[1][0], 0, 0, 0);
                O[1][1] = __builtin_amdgcn_mfma_f32_32x32x16_bf16(pf1, vf1, O[1][1], 0, 0, 0);
            }
        }
        __builtin_amdgcn_s_setprio(0);

        if (jt < 31) {                           // prefetch V_{t+1} -> other V buf
            const int j0n = jbase + (jt + 1) * 64;
#pragma unroll
            for (int t = 0; t < 4; ++t) {
                int gch = (w * 4 + t) * 64 + lane;
                int c = gch >> 3, sv = gch & 7;
                int jc = sv ^ (c & 7);
                gl2lds16(vB + ((size_t)(b * CCH + c) << 12) + j0n + jc * 8,
                         &lds[vbn + (w * 4 + t) * 1024]);
            }
        }
    }

    // ---- epilogue: unnormalized partial O (bf16) + deferred l reduce ----
    size_t pbase = (size_t)bx * (128 * 256);
#pragma unroll
    for (int ig = 0; ig < 2; ++ig)
#pragma unroll
        for (int cg = 0; cg < 2; ++cg)
#pragma unroll
            for (int r = 0; r < 16; ++r) {
                int i = ipb + ig * 32 + (r & 3) + 8 * (r >> 2) + 4 * lh;
                int c = cqb + cg * 32 + l31;
                pO[pbase + i * 256 + c] = f2bf(O[ig][cg][r]);
            }
#pragma unroll
    for (int r = 0; r < 16; ++r) {
        float l = l_acc[r];
        l += __shfl_xor(l, 1);
        l += __shfl_xor(l, 2);
        l += __shfl_xor(l, 4);
        l += __shfl_xor(l, 8);
        l += __shfl_xor(l, 16);
        if (l31 == 0) {                          // lanes 0 and 32 (rows +4 apart)
            int row = iqb + (r & 3) + 8 * (r >> 2) + 4 * lh;
            pml[bx * 256 + jh * 128 + row] = l;  // j-subhalf partial row sum
        }
    }
}

// ------- Kernel 6: proj MFMA GEMM with fused j-partial merge -------
// A-operand is reg-staged from the 2 pO partials, combined as
// (o0+o1)*fs[row] (fs from pml, precomputed in LDS), and written to the
// EXACT LDS image gl2lds produced (addr = r*4096 + w*1024 + lane*16).
// B (weights) stays gl2lds. Epilogue: bias + residual -> out fp32.
__global__ __launch_bounds__(256) void proj_mfma(
    const unsigned short* __restrict__ pO, const float* __restrict__ pml,
    const unsigned short* __restrict__ wb, const float* __restrict__ bp,
    const float* __restrict__ x, float* __restrict__ out) {
    __shared__ __align__(16) char lds[35328];    // 34816 + 512 for fs
    float* fs = (float*)&lds[34816];
    const int tid = threadIdx.x, lane = tid & 63, w = tid >> 6;
    const int ln15 = lane & 15, q = lane >> 4;
    const int n0 = blockIdx.x * 128;
    const int co0 = blockIdx.y * 128;

    if (tid < 128) {                      // 1/l for the block's 128 rows
        int n = n0 + tid;
        int bb = n >> 12, pix = n & 4095, it = pix >> 7, ii = pix & 127;
        int base = (it * 8 + bb * 2) * 256 + ii;
        float l = pml[base] + pml[base + 128] + pml[base + 256] + pml[base + 384];
        fs[tid] = 1.0f / l;
    }
    __syncthreads();

    f32x4 acc[2][8];
#pragma unroll
    for (int i2 = 0; i2 < 2; ++i2)
#pragma unroll
        for (int nf = 0; nf < 8; ++nf) {
            acc[i2][nf][0] = 0.f; acc[i2][nf][1] = 0.f;
            acc[i2][nf][2] = 0.f; acc[i2][nf][3] = 0.f;
        }

#pragma unroll 1
    for (int kt = 0; kt < 4; ++kt) {
#pragma unroll
        for (int r = 0; r < 4; ++r) {     // B staging (gl2lds, unchanged)
            int gch = r * 256 + tid;
            int row = gch >> 3, sidx = gch & 7;
            int cc = sidx ^ (row & 7);
            gl2lds16(wb + ((size_t)(co0 + row) << 8) + kt * 64 + cc * 8,
                     &lds[16384 + r * 4096 + w * 1024]);
        }
#pragma unroll
        for (int r = 0; r < 4; ++r) {     // A staging: merge-on-load from pO
            int gch = r * 256 + tid;
            int row = gch >> 3, sidx = gch & 7;
            int cc = sidx ^ (row & 7);
            int c = kt * 64 + cc * 8;
            int n = n0 + row;
            int bb = n >> 12, pix = n & 4095, it = pix >> 7, ii = pix & 127;
            size_t pb = (size_t)(it * 8 + bb * 2) * 32768 + (size_t)ii * 256 + c;
            uint4 a0 = *(const uint4*)&pO[pb];
            uint4 a1 = *(const uint4*)&pO[pb + 32768];
            float f = fs[row];
            uint4 o;
            o.x = comb2(a0.x, a1.x, f);
            o.y = comb2(a0.y, a1.y, f);
            o.z = comb2(a0.z, a1.z, f);
            o.w = comb2(a0.w, a1.w, f);
            *(uint4*)&lds[r * 4096 + w * 1024 + lane * 16] = o;
        }
        __syncthreads();
#pragma unroll
        for (int kk = 0; kk < 2; ++kk) {
            int kc = kk * 4 + q;
            bf16x8 af[2], bf[8];
#pragma unroll
            for (int i2 = 0; i2 < 2; ++i2) {
                int row = w * 32 + i2 * 16 + ln15;
                af[i2] = *(const bf16x8*)&lds[row * 128 + ((kc ^ (row & 7)) << 4)];
            }
#pragma unroll
            for (int nf = 0; nf < 8; ++nf) {
                int row = nf * 16 + ln15;
                bf[nf] = *(const bf16x8*)&lds[16384 + row * 128 + ((kc ^ (row & 7)) << 4)];
            }
#pragma unroll
            for (int i2 = 0; i2 < 2; ++i2)
#pragma unroll
                for (int nf = 0; nf < 8; ++nf)
                    acc[i2][nf] = __builtin_amdgcn_mfma_f32_16x16x32_bf16(
                        af[i2], bf[nf], acc[i2][nf], 0, 0, 0);
        }
        __syncthreads();
    }

    unsigned short* T = (unsigned short*)lds;
#pragma unroll
    for (int i2 = 0; i2 < 2; ++i2)
#pragma unroll
        for (int nf = 0; nf < 8; ++nf)
#pragma unroll
            for (int r = 0; r < 4; ++r) {
                int n_l = w * 32 + i2 * 16 + q * 4 + r;
                int co_l = nf * 16 + ln15;
                T[co_l * 136 + n_l] = f2bf(acc[i2][nf][r]);
            }
    __syncthreads();
    int row = tid >> 1, half = tid & 1;       // row = co_local
    int b2 = n0 >> 12, pix0 = n0 & 4095;
    float br = bp[co0 + row];
    size_t gidx = (((size_t)(b2 * CCH + co0 + row)) << 12) + pix0 + half * 64;
    const unsigned short* trow = &T[row * 136 + half * 64];
#pragma unroll
    for (int u = 0; u < 16; ++u) {
        float4 xv = *(const float4*)&x[gidx + u * 4];
        ushort4 tv = *(const ushort4*)&trow[u * 4];
        float4 o;
        o.x = xv.x + br + bf2f(tv.x);
        o.y = xv.y + br + bf2f(tv.y);
        o.z = xv.z + br + bf2f(tv.z);
        o.w = xv.w + br + bf2f(tv.w);
        *(float4*)&out[gidx + u * 4] = o;
    }
}

extern "C" void kernel_launch(void* const* d_in, const int* in_sizes, int n_in,
                              void* d_out, int out_size, void* d_ws, size_t ws_size,
                              hipStream_t stream) {
    const float* x     = (const float*)d_in[0];
    const float* gamma = (const float*)d_in[1];
    const float* beta  = (const float*)d_in[2];
    const float* wq    = (const float*)d_in[3];
    const float* bq    = (const float*)d_in[4];
    const float* wk    = (const float*)d_in[5];
    const float* bk    = (const float*)d_in[6];
    const float* wv    = (const float*)d_in[7];
    const float* bv    = (const float*)d_in[8];
    const float* wp    = (const float*)d_in[9];
    const float* bp    = (const float*)d_in[10];
    float* out = (float*)d_out;

    char* p = (char*)d_ws;
    unsigned short* sb  = (unsigned short*)p; p += 8388608;        // 8 MB
    unsigned short* wb  = (unsigned short*)p; p += 524288;         // 512 KB
    unsigned short* pO  = (unsigned short*)p; p += 16777216;       // 16 MB
    float*          pml = (float*)p;          p += 262144;         // 256 KB
    unsigned short* qT  = (unsigned short*)p; p += 8388608;        // 8 MB
    unsigned short* kT  = (unsigned short*)p; p += 8388608;        // 8 MB
    unsigned short* vB  = (unsigned short*)p;                      // 8 MB

    gn_fused<<<160, 512, 0, stream>>>(x, gamma, beta, wq, wk, wv, wp, sb, wb);
    qkv_mfma<<<dim3(128, 2, 3), 256, 0, stream>>>(sb, wb, bq, bk, bv, qT, kT, vB);
    attn_mfma<<<256, 512, 0, stream>>>(qT, kT, vB, pO, pml);
    proj_mfma<<<dim3(128, 2), 256, 0, stream>>>(pO, pml, wb, bp, x, out);
}

// Round 17
// 208.540 us; speedup vs baseline: 1.4856x; 1.0066x over previous
//
#include <hip/hip_runtime.h>

#define BB 4
#define CCH 256
#define NPIX 4096
#define EPS 1e-6f

typedef __attribute__((ext_vector_type(8))) short bf16x8;
typedef __attribute__((ext_vector_type(4))) float f32x4;
typedef __attribute__((ext_vector_type(16))) float f32x16;

__device__ __forceinline__ unsigned short f2bf(float f) {
    return (unsigned short)((__float_as_uint(f) + 0x8000u) >> 16);
}
__device__ __forceinline__ float bf2f(unsigned short h) {
    return __uint_as_float((unsigned)h << 16);
}
__device__ __forceinline__ void gl2lds16(const void* g, void* l) {
    __builtin_amdgcn_global_load_lds(
        (const __attribute__((address_space(1))) unsigned int*)g,
        (__attribute__((address_space(3))) unsigned int*)l, 16, 0, 0);
}
// combine two bf16x2 words: (a+b)*f per lane, repack to bf16x2
__device__ __forceinline__ unsigned int comb2(unsigned int u0, unsigned int u1,
                                              float f) {
    float lo = (bf2f((unsigned short)u0) + bf2f((unsigned short)u1)) * f;
    float hi = (bf2f((unsigned short)(u0 >> 16)) +
                bf2f((unsigned short)(u1 >> 16))) * f;
    return (unsigned int)f2bf(lo) | ((unsigned int)f2bf(hi) << 16);
}

// ------- Kernel 1: fused GroupNorm (stats + apply) + weight cvt -------
// Blocks 0..127: one block per (b,g). Stats pass reads the group's 128 KB
// slice (L2-resident), wave-shfl + 8-slot LDS reduce, then the apply pass
// re-reads from L2 and writes sb[n][c] bf16 (transposed). Blocks 128..159:
// weights fp32 -> bf16 (order p,q,k,v), 512 threads each.
__global__ __launch_bounds__(512) void gn_fused(
    const float* __restrict__ x, const float* __restrict__ gamma,
    const float* __restrict__ beta,
    const float* __restrict__ wq, const float* __restrict__ wk,
    const float* __restrict__ wv, const float* __restrict__ wp,
    unsigned short* __restrict__ sb, unsigned short* __restrict__ wb) {
    int bid = blockIdx.x;
    int t = threadIdx.x;
    if (bid >= 128) {                     // folded weight conversion
        int e = (bid - 128) * 512 + t;    // float4 index, 0..16383
        const float* srcs[4] = {wp, wq, wk, wv};
#pragma unroll
        for (int m = 0; m < 4; ++m) {
            float4 v = ((const float4*)srcs[m])[e];
            ushort4 hh;
            hh.x = f2bf(v.x); hh.y = f2bf(v.y);
            hh.z = f2bf(v.z); hh.w = f2bf(v.w);
            *(ushort4*)(wb + (size_t)m * 65536 + (size_t)e * 4) = hh;
        }
        return;
    }
    int b = bid >> 5, g = bid & 31;
    const float4* x4 = (const float4*)(x + (size_t)(b * CCH + g * 8) * NPIX);
    float s = 0.f, ss = 0.f;
    for (int e = t; e < 8192; e += 512) {
        float4 v = x4[e];
        s += v.x + v.y + v.z + v.w;
        ss += v.x * v.x + v.y * v.y + v.z * v.z + v.w * v.w;
    }
#pragma unroll
    for (int off = 1; off < 64; off <<= 1) {
        s += __shfl_xor(s, off);
        ss += __shfl_xor(ss, off);
    }
    __shared__ float ws[8], wss[8];
    int w = t >> 6, lane = t & 63;
    if (lane == 0) { ws[w] = s; wss[w] = ss; }
    __syncthreads();
    float S = 0.f, SS = 0.f;
#pragma unroll
    for (int i = 0; i < 8; ++i) { S += ws[i]; SS += wss[i]; }
    const float inv = 1.0f / (float)(8 * NPIX);
    float m = S * inv;
    float var = SS * inv - m * m;
    float rstd = rsqrtf(var + EPS);
    float scale[8], shift[8];
#pragma unroll
    for (int ci = 0; ci < 8; ++ci) {
        float ga = gamma[g * 8 + ci], be = beta[g * 8 + ci];
        scale[ci] = rstd * ga;
        shift[ci] = be - m * scale[ci];
    }
#pragma unroll 1
    for (int r = 0; r < 2; ++r) {
        int pq = r * 512 + t;                    // pixel-quad 0..1023
        __align__(16) unsigned short hh[4][8];
#pragma unroll
        for (int ci = 0; ci < 8; ++ci) {
            float4 v = x4[ci * 1024 + pq];       // L2-hit re-read
            hh[0][ci] = f2bf(v.x * scale[ci] + shift[ci]);
            hh[1][ci] = f2bf(v.y * scale[ci] + shift[ci]);
            hh[2][ci] = f2bf(v.z * scale[ci] + shift[ci]);
            hh[3][ci] = f2bf(v.w * scale[ci] + shift[ci]);
        }
        size_t base = ((size_t)(b * NPIX + pq * 4) << 8) + g * 8;
#pragma unroll
        for (int p = 0; p < 4; ++p)
            *(uint4*)(sb + base + (size_t)p * 256) = *(const uint4*)hh[p];
    }
}

// ------- Kernel 3: QKV MFMA GEMM (R11-verified, unchanged) -------
// C[n][co] = sum_c sb[n][c] * w[co][c]; block tile 128n x 128co, BK=64.
// z: 0=q (scaled, ->qT[n][c]), 1=k (->kT[n][c]), 2=v (->vB[c][n]).
__global__ __launch_bounds__(256) void qkv_mfma(
    const unsigned short* __restrict__ sb, const unsigned short* __restrict__ wb,
    const float* __restrict__ bq, const float* __restrict__ bk,
    const float* __restrict__ bv,
    unsigned short* __restrict__ qT, unsigned short* __restrict__ kT,
    unsigned short* __restrict__ vB) {
    __shared__ __align__(16) char lds[34816];
    const int tid = threadIdx.x, lane = tid & 63, w = tid >> 6;
    const int ln15 = lane & 15, q = lane >> 4;
    const int n0 = blockIdx.x * 128;
    const int co0 = blockIdx.y * 128;
    const int z = blockIdx.z;
    const unsigned short* wm = wb + (size_t)(z + 1) * 65536;
    const float* bias = (z == 0) ? bq : (z == 1) ? bk : bv;

    f32x4 acc[2][8];
#pragma unroll
    for (int i2 = 0; i2 < 2; ++i2)
#pragma unroll
        for (int nf = 0; nf < 8; ++nf) {
            acc[i2][nf][0] = 0.f; acc[i2][nf][1] = 0.f;
            acc[i2][nf][2] = 0.f; acc[i2][nf][3] = 0.f;
        }

#pragma unroll 1
    for (int kt = 0; kt < 4; ++kt) {
#pragma unroll
        for (int r = 0; r < 4; ++r) {
            int gch = r * 256 + tid;
            int row = gch >> 3, sidx = gch & 7;
            int cc = sidx ^ (row & 7);
            gl2lds16(sb + ((size_t)(n0 + row) << 8) + kt * 64 + cc * 8,
                     &lds[r * 4096 + w * 1024]);
            gl2lds16(wm + ((size_t)(co0 + row) << 8) + kt * 64 + cc * 8,
                     &lds[16384 + r * 4096 + w * 1024]);
        }
        __syncthreads();
#pragma unroll
        for (int kk = 0; kk < 2; ++kk) {
            int kc = kk * 4 + q;
            bf16x8 af[2], bf[8];
#pragma unroll
            for (int i2 = 0; i2 < 2; ++i2) {
                int row = w * 32 + i2 * 16 + ln15;
                af[i2] = *(const bf16x8*)&lds[row * 128 + ((kc ^ (row & 7)) << 4)];
            }
#pragma unroll
            for (int nf = 0; nf < 8; ++nf) {
                int row = nf * 16 + ln15;
                bf[nf] = *(const bf16x8*)&lds[16384 + row * 128 + ((kc ^ (row & 7)) << 4)];
            }
#pragma unroll
            for (int i2 = 0; i2 < 2; ++i2)
#pragma unroll
                for (int nf = 0; nf < 8; ++nf)
                    acc[i2][nf] = __builtin_amdgcn_mfma_f32_16x16x32_bf16(
                        af[i2], bf[nf], acc[i2][nf], 0, 0, 0);
        }
        __syncthreads();
    }

    // epilogue: bias (+scale for q), bounce through LDS tile for coalescing
    float bias_l[8];
#pragma unroll
    for (int nf = 0; nf < 8; ++nf) bias_l[nf] = bias[co0 + nf * 16 + ln15];
    const float scl = (z == 0) ? 0.0625f : 1.0f;
    unsigned short* T = (unsigned short*)lds;
    if (z < 2) {
#pragma unroll
        for (int i2 = 0; i2 < 2; ++i2)
#pragma unroll
            for (int nf = 0; nf < 8; ++nf)
#pragma unroll
                for (int r = 0; r < 4; ++r) {
                    int n_l = w * 32 + i2 * 16 + q * 4 + r;
                    int co_l = nf * 16 + ln15;
                    T[n_l * 136 + co_l] = f2bf((acc[i2][nf][r] + bias_l[nf]) * scl);
                }
    } else {
#pragma unroll
        for (int i2 = 0; i2 < 2; ++i2)
#pragma unroll
            for (int nf = 0; nf < 8; ++nf)
#pragma unroll
                for (int r = 0; r < 4; ++r) {
                    int n_l = w * 32 + i2 * 16 + q * 4 + r;
                    int co_l = nf * 16 + ln15;
                    T[co_l * 136 + n_l] = f2bf(acc[i2][nf][r] + bias_l[nf]);
                }
    }
    __syncthreads();
    int row = tid >> 1, half = tid & 1;
    const uint4* src = (const uint4*)&T[row * 136 + half * 64];
    uint4* dst;
    if (z < 2) {
        unsigned short* qk = (z == 0) ? qT : kT;
        dst = (uint4*)(qk + ((size_t)(n0 + row) << 8) + co0 + half * 64);
    } else {
        int b2 = n0 >> 12, pix0 = n0 & 4095;
        dst = (uint4*)(vB + ((size_t)(b2 * CCH + co0 + row) << 12) + pix0 + half * 64);
    }
#pragma unroll
    for (int u = 0; u < 8; ++u) dst[u] = src[u];
}

// ------- Kernel 4: flash attention, 32x32x16 MFMA, dbuf K/V, 2 barriers ----
// R12 structure; Q/K LDS swizzle is 5-bit (slot = sc ^ (row & 31), both
// staging-source and read side) making kf ds_read_b128 conflict-free
// (bank-conflict counter 8.5M -> 4.2M, verified R16). V (8-slot rows,
// gl2lds linear-dest constraint) and P keep the 3-bit swizzle.
// LDS: K0 0|K1 32K|V0 64K|V1 96K|P 128K..144K.
__global__ __launch_bounds__(512, 1) void attn_mfma(
    const unsigned short* __restrict__ qT, const unsigned short* __restrict__ kT,
    const unsigned short* __restrict__ vB,
    unsigned short* __restrict__ pO, float* __restrict__ pml) {
    __shared__ __align__(16) char lds[147456];
    const int tid = threadIdx.x, lane = tid & 63, w = tid >> 6;   // w 0..7
    const int l31 = lane & 31, lh = lane >> 5;
    const int bx = blockIdx.x;
    const int xk = bx & 7;                // XCD key = (b, bjh)
    const int b = xk >> 1, bjh = xk & 1;
    const int itile = bx >> 3;
    const int i0 = itile * 128;
    const int jbase = bjh * 2048;
    const size_t nb = (size_t)b * NPIX;
    const int iqb = (w >> 1) * 32;        // QK i-group base
    const int jh = w & 1, jwb = jh * 32;  // QK j-subhalf base
    const int ipb = (w & 1) * 64;         // PV i-half base
    const int cqb = (w >> 1) * 64;        // PV c-quarter base

    // ---- stage Q [128 i][256 c] (64 KB) into K0+K1 region (5-bit swz) ----
#pragma unroll
    for (int t = 0; t < 8; ++t) {
        int gch = (w * 8 + t) * 64 + lane;
        int row = gch >> 5, sc = gch & 31;
        int cc = sc ^ (row & 31);
        gl2lds16(qT + ((nb + i0 + row) << 8) + cc * 8, &lds[(w * 8 + t) * 1024]);
    }
    __syncthreads();
    bf16x8 qf[16];
    {
        int row = iqb + l31;              // A-frag: row = l&31, k = lh*8+e
#pragma unroll
        for (int kc = 0; kc < 16; ++kc) {
            int sc = kc * 2 + lh;
            qf[kc] = *(const bf16x8*)&lds[row * 512 + ((sc ^ (row & 31)) << 4)];
        }
    }
    __syncthreads();

    f32x16 O[2][2];
#pragma unroll
    for (int ig = 0; ig < 2; ++ig)
#pragma unroll
        for (int cg = 0; cg < 2; ++cg)
#pragma unroll
            for (int r = 0; r < 16; ++r) O[ig][cg][r] = 0.f;
    float l_acc[16];
#pragma unroll
    for (int r = 0; r < 16; ++r) l_acc[r] = 0.f;

    // ---- prologue prefetch: K_0 -> K0 (5-bit swz) then V_0 -> V0 ----
    {
        const int j0 = jbase;
#pragma unroll
        for (int t = 0; t < 4; ++t) {
            int gch = (w * 4 + t) * 64 + lane;
            int row = gch >> 5, sc = gch & 31;
            int cc = sc ^ (row & 31);
            gl2lds16(kT + ((nb + j0 + row) << 8) + cc * 8, &lds[(w * 4 + t) * 1024]);
        }
#pragma unroll
        for (int t = 0; t < 4; ++t) {
            int gch = (w * 4 + t) * 64 + lane;
            int c = gch >> 3, sv = gch & 7;
            int jc = sv ^ (c & 7);
            gl2lds16(vB + ((size_t)(b * CCH + c) << 12) + j0 + jc * 8,
                     &lds[65536 + (w * 4 + t) * 1024]);
        }
    }

#pragma unroll 1
    for (int jt = 0; jt < 32; ++jt) {
        const int kb_ = (jt & 1) * 32768;          // K buffer base
        const int vb_ = 65536 + (jt & 1) * 32768;  // V buffer base
        const int kbn = ((jt + 1) & 1) * 32768;
        const int vbn = 65536 + ((jt + 1) & 1) * 32768;

        // ---- K_t ready (oldest 4 loads = K_t; V_t may be in flight) ----
        asm volatile("s_waitcnt vmcnt(4)" ::: "memory");
        __builtin_amdgcn_s_barrier();            // (1) K_t staged, P slab free

        // ---- QK: S[32 i][32 j]; kf slots conflict-free (5-bit swz) ----
        f32x16 S0, S1;
#pragma unroll
        for (int r = 0; r < 16; ++r) { S0[r] = 0.f; S1[r] = 0.f; }
        __builtin_amdgcn_s_setprio(1);
        {
            int krow = jwb + l31;                // B-frag: col = l&31 (j)
            int ksw = kb_ + krow * 512;
            int kx = krow & 31;                  // = l31
#pragma unroll
            for (int kc = 0; kc < 8; ++kc) {
                int sc0 = (2 * kc) * 2 + lh;
                int sc1 = (2 * kc + 1) * 2 + lh;
                bf16x8 k0 = *(const bf16x8*)&lds[ksw + ((sc0 ^ kx) << 4)];
                bf16x8 k1 = *(const bf16x8*)&lds[ksw + ((sc1 ^ kx) << 4)];
                S0 = __builtin_amdgcn_mfma_f32_32x32x16_bf16(qf[2 * kc], k0, S0, 0, 0, 0);
                S1 = __builtin_amdgcn_mfma_f32_32x32x16_bf16(qf[2 * kc + 1], k1, S1, 0, 0, 0);
            }
        }
        __builtin_amdgcn_s_setprio(0);

        // ---- fixed-max softmax: p = exp(s); P -> slab; l per-lane ----
        {
            int col = jwb + l31;
            int chs = (col >> 3) << 4;
            int cof = (col & 7) << 1;
#pragma unroll
            for (int r = 0; r < 16; ++r) {
                float p = __expf(S0[r] + S1[r]);
                l_acc[r] += p;
                int row = iqb + (r & 3) + 8 * (r >> 2) + 4 * lh;
                *(unsigned short*)&lds[131072 + row * 128 +
                    (chs ^ ((row & 7) << 4)) + cof] = f2bf(p);
            }
        }
        asm volatile("s_waitcnt lgkmcnt(0)" ::: "memory");  // own P writes landed
        __builtin_amdgcn_sched_barrier(0);
        asm volatile("s_waitcnt vmcnt(0)" ::: "memory");    // V_t staged
        __builtin_amdgcn_s_barrier();            // (2) P visible + V_t + QK_t done

        if (jt < 31) {                           // prefetch K_{t+1} (5-bit swz)
            const int j0n = jbase + (jt + 1) * 64;
#pragma unroll
            for (int t = 0; t < 4; ++t) {
                int gch = (w * 4 + t) * 64 + lane;
                int row = gch >> 5, sc = gch & 31;
                int cc = sc ^ (row & 31);
                gl2lds16(kT + ((nb + j0n + row) << 8) + cc * 8,
                         &lds[kbn + (w * 4 + t) * 1024]);
            }
        }

        // ---- PV: O[64 i][64 c] += P[64 i][64 j] V[64 j][64 c] ----
        __builtin_amdgcn_s_setprio(1);
        {
            int pr0 = ipb + l31, pr1 = ipb + 32 + l31;   // P A-frag rows
            int vc0 = cqb + l31, vc1 = cqb + 32 + l31;   // V B-frag rows (c)
#pragma unroll
            for (int kc = 0; kc < 4; ++kc) {
                int pc = kc * 2 + lh;                     // j-chunk index
                bf16x8 pf0 = *(const bf16x8*)&lds[131072 + pr0 * 128 + ((pc ^ (pr0 & 7)) << 4)];
                bf16x8 pf1 = *(const bf16x8*)&lds[131072 + pr1 * 128 + ((pc ^ (pr1 & 7)) << 4)];
                bf16x8 vf0 = *(const bf16x8*)&lds[vb_ + vc0 * 128 + ((pc ^ (vc0 & 7)) << 4)];
                bf16x8 vf1 = *(const bf16x8*)&lds[vb_ + vc1 * 128 + ((pc ^ (vc1 & 7)) << 4)];
                O[0][0] = __builtin_amdgcn_mfma_f32_32x32x16_bf16(pf0, vf0, O[0][0], 0, 0, 0);
                O[0][1] = __builtin_amdgcn_mfma_f32_32x32x16_bf16(pf0, vf1, O[0][1], 0, 0, 0);
                O[1][0] = __builtin_amdgcn_mfma_f32_32x32x16_bf16(pf1, vf0, O[1][0], 0, 0, 0);
                O[1][1] = __builtin_amdgcn_mfma_f32_32x32x16_bf16(pf1, vf1, O[1][1], 0, 0, 0);
            }
        }
        __builtin_amdgcn_s_setprio(0);

        if (jt < 31) {                           // prefetch V_{t+1} -> other V buf
            const int j0n = jbase + (jt + 1) * 64;
#pragma unroll
            for (int t = 0; t < 4; ++t) {
                int gch = (w * 4 + t) * 64 + lane;
                int c = gch >> 3, sv = gch & 7;
                int jc = sv ^ (c & 7);
                gl2lds16(vB + ((size_t)(b * CCH + c) << 12) + j0n + jc * 8,
                         &lds[vbn + (w * 4 + t) * 1024]);
            }
        }
    }

    // ---- epilogue: unnormalized partial O (bf16) + deferred l reduce ----
    size_t pbase = (size_t)bx * (128 * 256);
#pragma unroll
    for (int ig = 0; ig < 2; ++ig)
#pragma unroll
        for (int cg = 0; cg < 2; ++cg)
#pragma unroll
            for (int r = 0; r < 16; ++r) {
                int i = ipb + ig * 32 + (r & 3) + 8 * (r >> 2) + 4 * lh;
                int c = cqb + cg * 32 + l31;
                pO[pbase + i * 256 + c] = f2bf(O[ig][cg][r]);
            }
#pragma unroll
    for (int r = 0; r < 16; ++r) {
        float l = l_acc[r];
        l += __shfl_xor(l, 1);
        l += __shfl_xor(l, 2);
        l += __shfl_xor(l, 4);
        l += __shfl_xor(l, 8);
        l += __shfl_xor(l, 16);
        if (l31 == 0) {                          // lanes 0 and 32 (rows +4 apart)
            int row = iqb + (r & 3) + 8 * (r >> 2) + 4 * lh;
            pml[bx * 256 + jh * 128 + row] = l;  // j-subhalf partial row sum
        }
    }
}

// ------- Kernel 6: proj MFMA GEMM with fused j-partial merge -------
// A-operand is reg-staged from the 2 pO partials, combined as
// (o0+o1)*fs[row] (fs from pml, precomputed in LDS), and written to the
// EXACT LDS image gl2lds produced (addr = r*4096 + w*1024 + lane*16).
// B (weights) stays gl2lds. Epilogue: bias + residual -> out fp32.
__global__ __launch_bounds__(256) void proj_mfma(
    const unsigned short* __restrict__ pO, const float* __restrict__ pml,
    const unsigned short* __restrict__ wb, const float* __restrict__ bp,
    const float* __restrict__ x, float* __restrict__ out) {
    __shared__ __align__(16) char lds[35328];    // 34816 + 512 for fs
    float* fs = (float*)&lds[34816];
    const int tid = threadIdx.x, lane = tid & 63, w = tid >> 6;
    const int ln15 = lane & 15, q = lane >> 4;
    const int n0 = blockIdx.x * 128;
    const int co0 = blockIdx.y * 128;

    if (tid < 128) {                      // 1/l for the block's 128 rows
        int n = n0 + tid;
        int bb = n >> 12, pix = n & 4095, it = pix >> 7, ii = pix & 127;
        int base = (it * 8 + bb * 2) * 256 + ii;
        float l = pml[base] + pml[base + 128] + pml[base + 256] + pml[base + 384];
        fs[tid] = 1.0f / l;
    }
    __syncthreads();

    f32x4 acc[2][8];
#pragma unroll
    for (int i2 = 0; i2 < 2; ++i2)
#pragma unroll
        for (int nf = 0; nf < 8; ++nf) {
            acc[i2][nf][0] = 0.f; acc[i2][nf][1] = 0.f;
            acc[i2][nf][2] = 0.f; acc[i2][nf][3] = 0.f;
        }

#pragma unroll 1
    for (int kt = 0; kt < 4; ++kt) {
#pragma unroll
        for (int r = 0; r < 4; ++r) {     // B staging (gl2lds, unchanged)
            int gch = r * 256 + tid;
            int row = gch >> 3, sidx = gch & 7;
            int cc = sidx ^ (row & 7);
            gl2lds16(wb + ((size_t)(co0 + row) << 8) + kt * 64 + cc * 8,
                     &lds[16384 + r * 4096 + w * 1024]);
        }
#pragma unroll
        for (int r = 0; r < 4; ++r) {     // A staging: merge-on-load from pO
            int gch = r * 256 + tid;
            int row = gch >> 3, sidx = gch & 7;
            int cc = sidx ^ (row & 7);
            int c = kt * 64 + cc * 8;
            int n = n0 + row;
            int bb = n >> 12, pix = n & 4095, it = pix >> 7, ii = pix & 127;
            size_t pb = (size_t)(it * 8 + bb * 2) * 32768 + (size_t)ii * 256 + c;
            uint4 a0 = *(const uint4*)&pO[pb];
            uint4 a1 = *(const uint4*)&pO[pb + 32768];
            float f = fs[row];
            uint4 o;
            o.x = comb2(a0.x, a1.x, f);
            o.y = comb2(a0.y, a1.y, f);
            o.z = comb2(a0.z, a1.z, f);
            o.w = comb2(a0.w, a1.w, f);
            *(uint4*)&lds[r * 4096 + w * 1024 + lane * 16] = o;
        }
        __syncthreads();
#pragma unroll
        for (int kk = 0; kk < 2; ++kk) {
            int kc = kk * 4 + q;
            bf16x8 af[2], bf[8];
#pragma unroll
            for (int i2 = 0; i2 < 2; ++i2) {
                int row = w * 32 + i2 * 16 + ln15;
                af[i2] = *(const bf16x8*)&lds[row * 128 + ((kc ^ (row & 7)) << 4)];
            }
#pragma unroll
            for (int nf = 0; nf < 8; ++nf) {
                int row = nf * 16 + ln15;
                bf[nf] = *(const bf16x8*)&lds[16384 + row * 128 + ((kc ^ (row & 7)) << 4)];
            }
#pragma unroll
            for (int i2 = 0; i2 < 2; ++i2)
#pragma unroll
                for (int nf = 0; nf < 8; ++nf)
                    acc[i2][nf] = __builtin_amdgcn_mfma_f32_16x16x32_bf16(
                        af[i2], bf[nf], acc[i2][nf], 0, 0, 0);
        }
        __syncthreads();
    }

    unsigned short* T = (unsigned short*)lds;
#pragma unroll
    for (int i2 = 0; i2 < 2; ++i2)
#pragma unroll
        for (int nf = 0; nf < 8; ++nf)
#pragma unroll
            for (int r = 0; r < 4; ++r) {
                int n_l = w * 32 + i2 * 16 + q * 4 + r;
                int co_l = nf * 16 + ln15;
                T[co_l * 136 + n_l] = f2bf(acc[i2][nf][r]);
            }
    __syncthreads();
    int row = tid >> 1, half = tid & 1;       // row = co_local
    int b2 = n0 >> 12, pix0 = n0 & 4095;
    float br = bp[co0 + row];
    size_t gidx = (((size_t)(b2 * CCH + co0 + row)) << 12) + pix0 + half * 64;
    const unsigned short* trow = &T[row * 136 + half * 64];
#pragma unroll
    for (int u = 0; u < 16; ++u) {
        float4 xv = *(const float4*)&x[gidx + u * 4];
        ushort4 tv = *(const ushort4*)&trow[u * 4];
        float4 o;
        o.x = xv.x + br + bf2f(tv.x);
        o.y = xv.y + br + bf2f(tv.y);
        o.z = xv.z + br + bf2f(tv.z);
        o.w = xv.w + br + bf2f(tv.w);
        *(float4*)&out[gidx + u * 4] = o;
    }
}

extern "C" void kernel_launch(void* const* d_in, const int* in_sizes, int n_in,
                              void* d_out, int out_size, void* d_ws, size_t ws_size,
                              hipStream_t stream) {
    const float* x     = (const float*)d_in[0];
    const float* gamma = (const float*)d_in[1];
    const float* beta  = (const float*)d_in[2];
    const float* wq    = (const float*)d_in[3];
    const float* bq    = (const float*)d_in[4];
    const float* wk    = (const float*)d_in[5];
    const float* bk    = (const float*)d_in[6];
    const float* wv    = (const float*)d_in[7];
    const float* bv    = (const float*)d_in[8];
    const float* wp    = (const float*)d_in[9];
    const float* bp    = (const float*)d_in[10];
    float* out = (float*)d_out;

    char* p = (char*)d_ws;
    unsigned short* sb  = (unsigned short*)p; p += 8388608;        // 8 MB
    unsigned short* wb  = (unsigned short*)p; p += 524288;         // 512 KB
    unsigned short* pO  = (unsigned short*)p; p += 16777216;       // 16 MB
    float*          pml = (float*)p;          p += 262144;         // 256 KB
    unsigned short* qT  = (unsigned short*)p; p += 8388608;        // 8 MB
    unsigned short* kT  = (unsigned short*)p; p += 8388608;        // 8 MB
    unsigned short* vB  = (unsigned short*)p;                      // 8 MB

    gn_fused<<<160, 512, 0, stream>>>(x, gamma, beta, wq, wk, wv, wp, sb, wb);
    qkv_mfma<<<dim3(128, 2, 3), 256, 0, stream>>>(sb, wb, bq, bk, bv, qT, kT, vB);
    attn_mfma<<<256, 512, 0, stream>>>(qT, kT, vB, pO, pml);
    proj_mfma<<<dim3(128, 2), 256, 0, stream>>>(pO, pml, wb, bp, x, out);
}